// Round 15
// baseline (220.789 us; speedup 1.0000x reference)
//
#include <hip/hip_runtime.h>

typedef unsigned short u16;
typedef __attribute__((ext_vector_type(8))) __bf16 bf16x8;
typedef __attribute__((ext_vector_type(2))) __bf16 bf16x2;
typedef __attribute__((ext_vector_type(4))) float f32x4;
typedef __attribute__((ext_vector_type(16))) float f32x16;
typedef __attribute__((ext_vector_type(2))) unsigned u32x2;

#define NB 2
#define NS 2048
#define ND 2048
#define NH 16
#define NKH 2
#define NHD 128
#define NQKV 2560
// 1/sqrt(128) * log2(e): scores in log2 domain -> exp2f = raw v_exp_f32
#define QSCALE (0.08838834764831845f * 1.4426950408889634f)

#define AS1 __attribute__((address_space(1)))
#define AS3 __attribute__((address_space(3)))

__device__ __forceinline__ u16 f2bf(float x) {
    union { float f; unsigned u; } v; v.f = x;
    unsigned r = v.u + 0x7fffu + ((v.u >> 16) & 1u);
    return (u16)(r >> 16);
}
__device__ __forceinline__ float bf2f(u16 x) {
    union { unsigned u; float f; } v; v.u = ((unsigned)x) << 16;
    return v.f;
}
__device__ __forceinline__ unsigned pk2(float lo, float hi_) {
    union { bf16x2 v; unsigned u; } t;
    t.v.x = (__bf16)lo; t.v.y = (__bf16)hi_;
    return t.u;
}
__device__ __forceinline__ void pl32swap(unsigned &a, unsigned &b) {
#if __has_builtin(__builtin_amdgcn_permlane32_swap)
    u32x2 r = __builtin_amdgcn_permlane32_swap(a, b, false, false);
    a = r.x; b = r.y;
#else
    asm volatile("v_permlane32_swap_b32 %0, %1" : "+v"(a), "+v"(b));
#endif
}
__device__ __forceinline__ float fbits(unsigned u) {
    union { unsigned u; float f; } v; v.u = u; return v.f;
}
__device__ __forceinline__ unsigned ubits(float f) {
    union { float f; unsigned u; } v; v.f = f; return v.u;
}
__device__ __forceinline__ float redmax32(float x) {
    unsigned a = ubits(x), b = a;
    pl32swap(a, b);
    return fmaxf(fbits(a), fbits(b));
}
__device__ __forceinline__ float redsum32(float x) {
    unsigned a = ubits(x), b = a;
    pl32swap(a, b);
    return fbits(a) + fbits(b);
}

// ---------------- fp32 -> bf16 conversion: all three inputs, one launch ----------------
__global__ void cvt_all(const float* __restrict__ a, u16* __restrict__ oa, int na,
                        const float* __restrict__ b, u16* __restrict__ ob, int nb,
                        const float* __restrict__ c, u16* __restrict__ oc, int nc)
{
    int i = blockIdx.x * 256 + threadIdx.x;
    const float* src; u16* dst;
    if (i < na)            { src = a; dst = oa; }
    else if (i < na + nb)  { src = b; dst = ob; i -= na; }
    else if (i < na + nb + nc) { src = c; dst = oc; i -= na + nb; }
    else return;
    float4 v = ((const float4*)src)[i];
    ushort4 o;
    o.x = f2bf(v.x); o.y = f2bf(v.y); o.z = f2bf(v.z); o.w = f2bf(v.w);
    ((ushort4*)dst)[i] = o;
}

// ---------------- GEMM: C[M,N] = A[M,K] * B[N,K]^T (+bias), XCD-swizzled 1D grid ----------------
template<int BIAS, int OUTBF16>
__global__ __launch_bounds__(256, 2)
void gemm_bt(const u16* __restrict__ A, const u16* __restrict__ B,
             const float* __restrict__ bias, void* __restrict__ Cout,
             int M, int N, int K, int mt, int nwg)
{
    __shared__ u16 lds[2][2][8192];
    const int l = threadIdx.x & 63;
    const int w = threadIdx.x >> 6;
    const int bid = blockIdx.x;
    const int wg = (bid & 7) * (nwg >> 3) + (bid >> 3);
    const int m0 = (wg % mt) * 128, n0 = (wg / mt) * 128;
    const int wm = (w >> 1) * 64, wn = (w & 1) * 64;
    f32x4 acc[4][4] = {};

    const int lbyte = ((l & 7) * 16) ^ ((l >> 3) << 4);

    auto stage = [&](int buf, int k0) {
        #pragma unroll
        for (int inst = 0; inst < 4; ++inst) {
            int row = inst * 32 + w * 8 + (l >> 3);
            const u16* sa = A + (size_t)(m0 + row) * K + k0 + (lbyte >> 1);
            const u16* sb = B + (size_t)(n0 + row) * K + k0 + (lbyte >> 1);
            __builtin_amdgcn_global_load_lds(
                (const AS1 void*)sa,
                (AS3 void*)&lds[buf][0][inst * 2048 + w * 512], 16, 0, 0);
            __builtin_amdgcn_global_load_lds(
                (const AS1 void*)sb,
                (AS3 void*)&lds[buf][1][inst * 2048 + w * 512], 16, 0, 0);
        }
    };

    auto compute = [&](int buf) {
        const char* Ab = (const char*)&lds[buf][0][0];
        const char* Bb = (const char*)&lds[buf][1][0];
        #pragma unroll
        for (int kk = 0; kk < 2; ++kk) {
            int ac2 = kk * 64 + (l >> 4) * 16;
            bf16x8 af[4], bfr[4];
            #pragma unroll
            for (int i = 0; i < 4; ++i) {
                int ar = wm + i * 16 + (l & 15);
                af[i] = *(const bf16x8*)(Ab + ar * 128 + (ac2 ^ ((ar & 7) << 4)));
                int br = wn + i * 16 + (l & 15);
                bfr[i] = *(const bf16x8*)(Bb + br * 128 + (ac2 ^ ((br & 7) << 4)));
            }
            #pragma unroll
            for (int i = 0; i < 4; ++i)
                #pragma unroll
                for (int j = 0; j < 4; ++j)
                    acc[i][j] = __builtin_amdgcn_mfma_f32_16x16x32_bf16(af[i], bfr[j], acc[i][j], 0, 0, 0);
        }
    };

    stage(0, 0);
    const int NT = K >> 6;
    for (int kt = 0; kt < NT; ++kt) {
        __syncthreads();
        if (kt + 1 < NT) stage((kt + 1) & 1, (kt + 1) << 6);
        compute(kt & 1);
    }

    #pragma unroll
    for (int j = 0; j < 4; ++j) {
        int col = n0 + wn + j * 16 + (l & 15);
        float bv = BIAS ? bias[col] : 0.0f;
        #pragma unroll
        for (int i = 0; i < 4; ++i) {
            int row = m0 + wm + i * 16 + (l >> 4) * 4;
            #pragma unroll
            for (int r = 0; r < 4; ++r) {
                float v = acc[i][j][r] + bv;
                if (OUTBF16)
                    ((u16*)Cout)[(size_t)(row + r) * N + col] = f2bf(v);
                else
                    ((float*)Cout)[(size_t)(row + r) * N + col] = v;
            }
        }
    }
}

// ---------------- RoPE + scatter, cos/sin-deduplicated ----------------
__global__ __launch_bounds__(256)
void rope_scatter2(const u16* __restrict__ qkv,
                   const float* __restrict__ cosb,
                   const float* __restrict__ sinb,
                   u16* __restrict__ Q, u16* __restrict__ Kb, u16* __restrict__ Vt)
{
    int n = blockIdx.x * 256 + threadIdx.x;       // [0, NB*NS*128)
    const int d = n & 127;
    const int bs = n >> 7;                        // b*NS + s
    const int b = bs >> 11, s = bs & 2047;

    const float cs = cosb[(size_t)bs * NHD + d];
    const float sn = sinb[(size_t)bs * NHD + d];
    const int pd = (d < 64) ? d + 64 : d - 64;
    const float psign = (d < 64) ? -1.0f : 1.0f;

    const u16* row = qkv + (size_t)bs * NQKV;

    #pragma unroll
    for (int h = 0; h < NH; ++h) {
        float x = bf2f(row[h * NHD + d]);
        float p = bf2f(row[h * NHD + pd]);
        float v = (x * cs + psign * p * sn) * QSCALE;
        Q[(((size_t)b * NH + h) * NS + s) * NHD + d] = f2bf(v);
    }
    #pragma unroll
    for (int kh = 0; kh < NKH; ++kh) {
        float x = bf2f(row[NH * NHD + kh * NHD + d]);
        float p = bf2f(row[NH * NHD + kh * NHD + pd]);
        float v = x * cs + psign * p * sn;
        Kb[(((size_t)b * NKH + kh) * NS + s) * NHD + d] = f2bf(v);
    }
    #pragma unroll
    for (int vh = 0; vh < NKH; ++vh) {
        Vt[(((size_t)b * NKH + vh) * NHD + d) * NS + s] = row[(NH + NKH) * NHD + vh * NHD + d];
    }
}

// ---------------- causal GQA flash attention v10 ----------------
// 512 blocks x 4 waves. Block = (hh, g): all 4 waves on the 128 contiguous
// q-rows of group g (wave w: rows g*128+w*32..+31); loops the exact causal
// range NT = 4g+4 tiles of 32 kv. LPT: g = 15-(bid>>5) -> 64-iter blocks
// dispatch first. K+V double-buffered in 32 KB LDS. ~96% active
// wave-iterations (vs 67% for v6's lo/hi pairing). Direct normalized write.
__global__ __launch_bounds__(256, 2)
void attn_fwd10(const u16* __restrict__ Q, const u16* __restrict__ Kb,
                const u16* __restrict__ Vt, u16* __restrict__ Out)
{
    __shared__ u16 kl[2][4096];   // K tile: [32 rows][128 d] bf16 = 8 KB per buf
    __shared__ u16 vl[2][4096];   // V tile: [128 d][32 kv] bf16 = 8 KB per buf

    const int l = threadIdx.x & 63;
    const int w = threadIdx.x >> 6;
    const int bid = blockIdx.x;
    const int g = 15 - (bid >> 5);            // 0..15, longest blocks first
    const int hh = bid & 31;                  // b*16+h
    const int h = hh & 15, b = hh >> 4;
    const int kh = h >> 3;
    const int c = l & 31, hi = l >> 5;
    const int q0 = g * 128 + w * 32;          // this wave's 32 q-rows

    const u16* Qp = Q + (((size_t)b * NH + h) * NS + q0) * NHD;
    const u16* Kp = Kb + ((size_t)b * NKH + kh) * NS * NHD;
    const u16* Vp = Vt + ((size_t)b * NKH + kh) * (size_t)NHD * NS;

    bf16x8 qf[8];
    #pragma unroll
    for (int ds = 0; ds < 8; ++ds)
        qf[ds] = *(const bf16x8*)(Qp + c * NHD + ds * 16 + hi * 8);

    f32x16 o0 = {}, o1 = {}, o2 = {}, o3 = {};
    float m_run = -1e30f, l_run = 0.f;

    // stage one 32-kv K/V tile pair (8 KB each): 2+2 global_load_lds per wave
    auto stage = [&](int buf, int t) {
        const int kb = t << 5;
        #pragma unroll
        for (int ii = 0; ii < 2; ++ii) {           // K: [32 rows][128 d]
            int row = (w * 2 + ii) * 4 + (l >> 4);
            int q = (l & 15) ^ (row & 7);
            const u16* src = Kp + (size_t)(kb + row) * NHD + q * 8;
            __builtin_amdgcn_global_load_lds(
                (const AS1 void*)src,
                (AS3 void*)&kl[buf][(w * 2 + ii) * 512], 16, 0, 0);
        }
        #pragma unroll
        for (int ii = 0; ii < 2; ++ii) {           // V: [128 d][32 kv]
            int d = (w * 2 + ii) * 16 + (l >> 2);
            int q = (l & 3) ^ ((l >> 3) & 3);      // f(d) = (d>>1)&3
            const u16* src = Vp + (size_t)d * NS + kb + q * 8;
            __builtin_amdgcn_global_load_lds(
                (const AS1 void*)src,
                (AS3 void*)&vl[buf][(w * 2 + ii) * 512], 16, 0, 0);
        }
    };

    const int NT = 4 * g + 4;                  // full causal range, 32-kv tiles
    stage(0, 0);
    __syncthreads();

    for (int t = 0; t < NT; ++t) {
        const int kb = t << 5;
        const int cur = t & 1;
        if (t + 1 < NT) stage(cur ^ 1, t + 1);

        if (kb <= q0) {                            // active tile for this wave
            const char* Klb = (const char*)kl[cur];
            const char* Vlb = (const char*)vl[cur];

            f32x16 s0 = {};
            __builtin_amdgcn_s_setprio(1);
            #pragma unroll
            for (int ds = 0; ds < 8; ++ds) {
                bf16x8 kf = *(const bf16x8*)(Klb + c * 256 + ((ds * 32 + hi * 16) ^ ((c & 7) << 4)));
                s0 = __builtin_amdgcn_mfma_f32_32x32x16_bf16(kf, qf[ds], s0, 0, 0, 0);
            }
            __builtin_amdgcn_s_setprio(0);

            float sv[16];
            #pragma unroll
            for (int rr = 0; rr < 16; ++rr) sv[rr] = s0[rr];

            if (kb == q0) {                        // diagonal tile: mask kk > c
                #pragma unroll
                for (int rr = 0; rr < 16; ++rr) {
                    int kk = (rr & 3) + 8 * (rr >> 2) + 4 * hi;
                    if (kk > c) sv[rr] = -1e30f;
                }
            }

            float mx = -1e30f;
            #pragma unroll
            for (int rr = 0; rr < 16; ++rr) mx = fmaxf(mx, sv[rr]);
            mx = redmax32(mx);

            if (__any(mx > m_run + 8.0f)) {        // defer-max (T13)
                float mnew = fmaxf(m_run, mx);
                float alpha = exp2f(m_run - mnew);
                m_run = mnew;
                l_run *= alpha;
                #pragma unroll
                for (int rr = 0; rr < 16; ++rr) {
                    int qr = (rr & 3) + 8 * (rr >> 2) + 4 * hi;
                    float aR = __shfl(alpha, qr + (l & 32));
                    o0[rr] *= aR; o1[rr] *= aR; o2[rr] *= aR; o3[rr] *= aR;
                }
            }

            float ls = 0.f;
            #pragma unroll
            for (int rr = 0; rr < 16; ++rr) {
                sv[rr] = exp2f(sv[rr] - m_run);
                ls += sv[rr];
            }
            l_run += redsum32(ls);

            // P -> A-fragments (2 permlane32_swap per ks)
            bf16x8 pa[2];
            #pragma unroll
            for (int ks = 0; ks < 2; ++ks) {
                const int b8 = ks * 8;
                unsigned A  = pk2(sv[b8 + 0], sv[b8 + 1]);
                unsigned Bq = pk2(sv[b8 + 4], sv[b8 + 5]);
                unsigned C2 = pk2(sv[b8 + 2], sv[b8 + 3]);
                unsigned D2 = pk2(sv[b8 + 6], sv[b8 + 7]);
                pl32swap(A, Bq);
                pl32swap(C2, D2);
                union { uint4 u; bf16x8 v; } cv;
                cv.u.x = A;
                cv.u.y = C2;
                cv.u.z = Bq;
                cv.u.w = D2;
                pa[ks] = cv.v;
            }

            // PV from LDS V tile ([128 d][32 kv], chunk-swizzled)
            __builtin_amdgcn_s_setprio(1);
            #pragma unroll
            for (int ks = 0; ks < 2; ++ks) {
                const int cs = (c >> 1) & 3;
                bf16x8 vf;
                vf = *(const bf16x8*)(Vlb + (0 * 32 + c) * 64 + (((ks * 2 + hi) ^ cs) << 4));
                o0 = __builtin_amdgcn_mfma_f32_32x32x16_bf16(pa[ks], vf, o0, 0, 0, 0);
                vf = *(const bf16x8*)(Vlb + (1 * 32 + c) * 64 + (((ks * 2 + hi) ^ cs) << 4));
                o1 = __builtin_amdgcn_mfma_f32_32x32x16_bf16(pa[ks], vf, o1, 0, 0, 0);
                vf = *(const bf16x8*)(Vlb + (2 * 32 + c) * 64 + (((ks * 2 + hi) ^ cs) << 4));
                o2 = __builtin_amdgcn_mfma_f32_32x32x16_bf16(pa[ks], vf, o2, 0, 0, 0);
                vf = *(const bf16x8*)(Vlb + (3 * 32 + c) * 64 + (((ks * 2 + hi) ^ cs) << 4));
                o3 = __builtin_amdgcn_mfma_f32_32x32x16_bf16(pa[ks], vf, o3, 0, 0, 0);
            }
            __builtin_amdgcn_s_setprio(0);
        }
        __syncthreads();
    }

    // direct normalized write (no split/merge)
    const float linv = 1.0f / l_run;
    #pragma unroll
    for (int rr = 0; rr < 16; ++rr) {
        int qr = (rr & 3) + 8 * (rr >> 2) + 4 * hi;
        float lr = __shfl(linv, qr + (l & 32));
        size_t base = ((size_t)(b * NS + q0 + qr)) * (NH * NHD) + h * NHD;
        Out[base + c]      = f2bf(o0[rr] * lr);
        Out[base + 32 + c] = f2bf(o1[rr] * lr);
        Out[base + 64 + c] = f2bf(o2[rr] * lr);
        Out[base + 96 + c] = f2bf(o3[rr] * lr);
    }
}

// ---------------- host launcher ----------------
extern "C" void kernel_launch(void* const* d_in, const int* in_sizes, int n_in,
                              void* d_out, int out_size, void* d_ws, size_t ws_size,
                              hipStream_t stream)
{
    (void)in_sizes; (void)n_in; (void)out_size; (void)ws_size;
    const float* hidden = (const float*)d_in[0];
    const float* cosb   = (const float*)d_in[1];
    const float* sinb   = (const float*)d_in[2];
    const float* qkv_w  = (const float*)d_in[3];
    const float* qkv_b  = (const float*)d_in[4];
    const float* o_w    = (const float*)d_in[5];
    float* out = (float*)d_out;

    char* ws = (char*)d_ws;
    size_t off = 0;
    auto alloc = [&](size_t bytes) {
        void* p = ws + off; off += (bytes + 255) & ~(size_t)255; return p;
    };
    u16* hid_bf  = (u16*)alloc((size_t)NB * NS * ND * 2);
    u16* qkvw_bf = (u16*)alloc((size_t)NQKV * ND * 2);
    u16* ow_bf   = (u16*)alloc((size_t)ND * NH * NHD * 2);
    u16* qkv     = (u16*)alloc((size_t)NB * NS * NQKV * 2);
    u16* Qb      = (u16*)alloc((size_t)NB * NH * NS * NHD * 2);
    u16* Kb      = (u16*)alloc((size_t)NB * NKH * NS * NHD * 2);
    u16* Vt      = (u16*)alloc((size_t)NB * NKH * NS * NHD * 2);
    u16* attn    = hid_bf;   // alias: hidden_bf16 dead after GEMM1

    int n1 = NB * NS * ND / 4;
    int n2 = NQKV * ND / 4;
    int n3 = ND * NH * NHD / 4;
    cvt_all<<<(n1 + n2 + n3 + 255) / 256, 256, 0, stream>>>(
        hidden, hid_bf, n1, qkv_w, qkvw_bf, n2, o_w, ow_bf, n3);

    int nwg1 = (NB * NS / 128) * (NQKV / 128);     // 640
    gemm_bt<1, 1><<<nwg1, 256, 0, stream>>>(hid_bf, qkvw_bf, qkv_b, qkv,
                                            NB * NS, NQKV, ND, NB * NS / 128, nwg1);

    int nr = NB * NS * NHD;                        // one thread per (bs, d)
    rope_scatter2<<<nr / 256, 256, 0, stream>>>(qkv, cosb, sinb, Qb, Kb, Vt);

    attn_fwd10<<<512, 256, 0, stream>>>(Qb, Kb, Vt, attn);

    int nwg2 = (NB * NS / 128) * (ND / 128);       // 512
    gemm_bt<0, 0><<<nwg2, 256, 0, stream>>>(attn, ow_bf, nullptr, out,
                                            NB * NS, ND, NH * NHD, NB * NS / 128, nwg2);
}

// Round 16
// 211.104 us; speedup vs baseline: 1.0459x; 1.0459x over previous
//
#include <hip/hip_runtime.h>

typedef unsigned short u16;
typedef __attribute__((ext_vector_type(8))) __bf16 bf16x8;
typedef __attribute__((ext_vector_type(2))) __bf16 bf16x2;
typedef __attribute__((ext_vector_type(4))) float f32x4;
typedef __attribute__((ext_vector_type(16))) float f32x16;
typedef __attribute__((ext_vector_type(2))) unsigned u32x2;

#define NB 2
#define NS 2048
#define ND 2048
#define NH 16
#define NKH 2
#define NHD 128
#define NQKV 2560
// 1/sqrt(128) * log2(e): scores in log2 domain -> exp2f = raw v_exp_f32
#define QSCALE (0.08838834764831845f * 1.4426950408889634f)

#define AS1 __attribute__((address_space(1)))
#define AS3 __attribute__((address_space(3)))

__device__ __forceinline__ u16 f2bf(float x) {
    union { float f; unsigned u; } v; v.f = x;
    unsigned r = v.u + 0x7fffu + ((v.u >> 16) & 1u);
    return (u16)(r >> 16);
}
__device__ __forceinline__ float bf2f(u16 x) {
    union { unsigned u; float f; } v; v.u = ((unsigned)x) << 16;
    return v.f;
}
__device__ __forceinline__ unsigned pk2(float lo, float hi_) {
    union { bf16x2 v; unsigned u; } t;
    t.v.x = (__bf16)lo; t.v.y = (__bf16)hi_;
    return t.u;
}
__device__ __forceinline__ void pl32swap(unsigned &a, unsigned &b) {
#if __has_builtin(__builtin_amdgcn_permlane32_swap)
    u32x2 r = __builtin_amdgcn_permlane32_swap(a, b, false, false);
    a = r.x; b = r.y;
#else
    asm volatile("v_permlane32_swap_b32 %0, %1" : "+v"(a), "+v"(b));
#endif
}
__device__ __forceinline__ float fbits(unsigned u) {
    union { unsigned u; float f; } v; v.u = u; return v.f;
}
__device__ __forceinline__ unsigned ubits(float f) {
    union { float f; unsigned u; } v; v.f = f; return v.u;
}
__device__ __forceinline__ float redmax32(float x) {
    unsigned a = ubits(x), b = a;
    pl32swap(a, b);
    return fmaxf(fbits(a), fbits(b));
}
__device__ __forceinline__ float redsum32(float x) {
    unsigned a = ubits(x), b = a;
    pl32swap(a, b);
    return fbits(a) + fbits(b);
}

// ---------------- fp32 -> bf16 conversion: all three inputs, one launch ----------------
__global__ void cvt_all(const float* __restrict__ a, u16* __restrict__ oa, int na,
                        const float* __restrict__ b, u16* __restrict__ ob, int nb,
                        const float* __restrict__ c, u16* __restrict__ oc, int nc)
{
    int i = blockIdx.x * 256 + threadIdx.x;
    const float* src; u16* dst;
    if (i < na)            { src = a; dst = oa; }
    else if (i < na + nb)  { src = b; dst = ob; i -= na; }
    else if (i < na + nb + nc) { src = c; dst = oc; i -= na + nb; }
    else return;
    float4 v = ((const float4*)src)[i];
    ushort4 o;
    o.x = f2bf(v.x); o.y = f2bf(v.y); o.z = f2bf(v.z); o.w = f2bf(v.w);
    ((ushort4*)dst)[i] = o;
}

// ---------------- GEMM: C[M,N] = A[M,K] * B[N,K]^T (+bias), XCD-swizzled 1D grid ----------------
template<int BIAS, int OUTBF16>
__global__ __launch_bounds__(256, 2)
void gemm_bt(const u16* __restrict__ A, const u16* __restrict__ B,
             const float* __restrict__ bias, void* __restrict__ Cout,
             int M, int N, int K, int mt, int nwg)
{
    __shared__ u16 lds[2][2][8192];
    const int l = threadIdx.x & 63;
    const int w = threadIdx.x >> 6;
    const int bid = blockIdx.x;
    const int wg = (bid & 7) * (nwg >> 3) + (bid >> 3);
    const int m0 = (wg % mt) * 128, n0 = (wg / mt) * 128;
    const int wm = (w >> 1) * 64, wn = (w & 1) * 64;
    f32x4 acc[4][4] = {};

    const int lbyte = ((l & 7) * 16) ^ ((l >> 3) << 4);

    auto stage = [&](int buf, int k0) {
        #pragma unroll
        for (int inst = 0; inst < 4; ++inst) {
            int row = inst * 32 + w * 8 + (l >> 3);
            const u16* sa = A + (size_t)(m0 + row) * K + k0 + (lbyte >> 1);
            const u16* sb = B + (size_t)(n0 + row) * K + k0 + (lbyte >> 1);
            __builtin_amdgcn_global_load_lds(
                (const AS1 void*)sa,
                (AS3 void*)&lds[buf][0][inst * 2048 + w * 512], 16, 0, 0);
            __builtin_amdgcn_global_load_lds(
                (const AS1 void*)sb,
                (AS3 void*)&lds[buf][1][inst * 2048 + w * 512], 16, 0, 0);
        }
    };

    auto compute = [&](int buf) {
        const char* Ab = (const char*)&lds[buf][0][0];
        const char* Bb = (const char*)&lds[buf][1][0];
        #pragma unroll
        for (int kk = 0; kk < 2; ++kk) {
            int ac2 = kk * 64 + (l >> 4) * 16;
            bf16x8 af[4], bfr[4];
            #pragma unroll
            for (int i = 0; i < 4; ++i) {
                int ar = wm + i * 16 + (l & 15);
                af[i] = *(const bf16x8*)(Ab + ar * 128 + (ac2 ^ ((ar & 7) << 4)));
                int br = wn + i * 16 + (l & 15);
                bfr[i] = *(const bf16x8*)(Bb + br * 128 + (ac2 ^ ((br & 7) << 4)));
            }
            #pragma unroll
            for (int i = 0; i < 4; ++i)
                #pragma unroll
                for (int j = 0; j < 4; ++j)
                    acc[i][j] = __builtin_amdgcn_mfma_f32_16x16x32_bf16(af[i], bfr[j], acc[i][j], 0, 0, 0);
        }
    };

    stage(0, 0);
    const int NT = K >> 6;
    for (int kt = 0; kt < NT; ++kt) {
        __syncthreads();
        if (kt + 1 < NT) stage((kt + 1) & 1, (kt + 1) << 6);
        compute(kt & 1);
    }

    #pragma unroll
    for (int j = 0; j < 4; ++j) {
        int col = n0 + wn + j * 16 + (l & 15);
        float bv = BIAS ? bias[col] : 0.0f;
        #pragma unroll
        for (int i = 0; i < 4; ++i) {
            int row = m0 + wm + i * 16 + (l >> 4) * 4;
            #pragma unroll
            for (int r = 0; r < 4; ++r) {
                float v = acc[i][j][r] + bv;
                if (OUTBF16)
                    ((u16*)Cout)[(size_t)(row + r) * N + col] = f2bf(v);
                else
                    ((float*)Cout)[(size_t)(row + r) * N + col] = v;
            }
        }
    }
}

// ---------------- RoPE + scatter, cos/sin-deduplicated ----------------
__global__ __launch_bounds__(256)
void rope_scatter2(const u16* __restrict__ qkv,
                   const float* __restrict__ cosb,
                   const float* __restrict__ sinb,
                   u16* __restrict__ Q, u16* __restrict__ Kb, u16* __restrict__ Vt)
{
    int n = blockIdx.x * 256 + threadIdx.x;       // [0, NB*NS*128)
    const int d = n & 127;
    const int bs = n >> 7;                        // b*NS + s
    const int b = bs >> 11, s = bs & 2047;

    const float cs = cosb[(size_t)bs * NHD + d];
    const float sn = sinb[(size_t)bs * NHD + d];
    const int pd = (d < 64) ? d + 64 : d - 64;
    const float psign = (d < 64) ? -1.0f : 1.0f;

    const u16* row = qkv + (size_t)bs * NQKV;

    #pragma unroll
    for (int h = 0; h < NH; ++h) {
        float x = bf2f(row[h * NHD + d]);
        float p = bf2f(row[h * NHD + pd]);
        float v = (x * cs + psign * p * sn) * QSCALE;
        Q[(((size_t)b * NH + h) * NS + s) * NHD + d] = f2bf(v);
    }
    #pragma unroll
    for (int kh = 0; kh < NKH; ++kh) {
        float x = bf2f(row[NH * NHD + kh * NHD + d]);
        float p = bf2f(row[NH * NHD + kh * NHD + pd]);
        float v = x * cs + psign * p * sn;
        Kb[(((size_t)b * NKH + kh) * NS + s) * NHD + d] = f2bf(v);
    }
    #pragma unroll
    for (int vh = 0; vh < NKH; ++vh) {
        Vt[(((size_t)b * NKH + vh) * NHD + d) * NS + s] = row[(NH + NKH) * NHD + vh * NHD + d];
    }
}

// ---------------- causal GQA flash attention v6 (best measured: 84 us) ----------------
__global__ __launch_bounds__(256, 2)
void attn_fwd6(const u16* __restrict__ Q, const u16* __restrict__ Kb,
               const u16* __restrict__ Vt, u16* __restrict__ Out)
{
    __shared__ u16 kl[2][8192];   // K tile: [64 rows][128 d] bf16, 16 KB per buf
    __shared__ u16 vl[2][8192];   // V tile: [128 d][64 kv] bf16, 16 KB per buf

    const int l = threadIdx.x & 63;
    const int w = threadIdx.x >> 6;
    const int i = blockIdx.x;
    const int s = i >> 8;                     // dispatch sweep 0/1
    const int j = i & 255;
    const int hh = j & 31;                    // b*16+h
    const int gp = s ? (15 - (j >> 5)) : (j >> 5);   // 0..15; long blocks first
    const int h = hh & 15, b = hh >> 4;
    const int kh = h >> 3;
    const int c = l & 31, hi = l >> 5;
    const int loWave = ((w >> 1) ^ s) == 0;
    const int grp = loWave ? gp : (31 - gp);
    const int q0 = grp * 64 + (w & 1) * 32;
    const int qend = q0 + 31;

    const u16* Qp = Q + (((size_t)b * NH + h) * NS + q0) * NHD;
    const u16* Kp = Kb + ((size_t)b * NKH + kh) * NS * NHD;
    const u16* Vp = Vt + ((size_t)b * NKH + kh) * (size_t)NHD * NS;

    bf16x8 qf[8];
    #pragma unroll
    for (int ds = 0; ds < 8; ++ds)
        qf[ds] = *(const bf16x8*)(Qp + c * NHD + ds * 16 + hi * 8);

    f32x16 o0 = {}, o1 = {}, o2 = {}, o3 = {};
    float m_run = -1e30f, l_run = 0.f;

    auto stage = [&](int buf, int kt) {
        const int kb = kt << 6;
        #pragma unroll
        for (int ii = 0; ii < 4; ++ii) {           // K: rows r, swizzled col chunks
            int r = w * 16 + ii * 4 + (l >> 4);
            int q = (l & 15) ^ ((ii * 4 + (l >> 4)) & 7);
            const u16* src = Kp + (size_t)(kb + r) * NHD + q * 8;
            __builtin_amdgcn_global_load_lds(
                (const AS1 void*)src,
                (AS3 void*)&kl[buf][(w * 4 + ii) * 512], 16, 0, 0);
        }
        #pragma unroll
        for (int ii = 0; ii < 4; ++ii) {           // V: rows d, swizzled kv chunks
            int jj = w * 4 + ii;
            int d = jj * 8 + (l >> 3);
            int q = (l & 7) ^ ((l >> 3) & 7);
            const u16* src = Vp + (size_t)d * NS + kb + q * 8;
            __builtin_amdgcn_global_load_lds(
                (const AS1 void*)src,
                (AS3 void*)&vl[buf][jj * 512], 16, 0, 0);
        }
    };

    const int NT = 32 - gp;
    stage(0, 0);
    __syncthreads();

    for (int kt = 0; kt < NT; ++kt) {
        const int kb = kt << 6;
        const int cur = kt & 1;
        if (kt + 1 < NT) stage(cur ^ 1, kt + 1);

        const bool do0 = (kb <= qend);
        const bool do1 = (kb + 32 <= qend);
        if (do0) {
            const bool diag0 = (kb == q0);
            const bool diag1 = (kb + 32 == q0);
            const char* Klb = (const char*)kl[cur];
            const char* Vlb = (const char*)vl[cur];

            f32x16 s0 = {}, s1 = {};
            __builtin_amdgcn_s_setprio(1);
            #pragma unroll
            for (int ds = 0; ds < 8; ++ds) {
                bf16x8 kf0 = *(const bf16x8*)(Klb + c * 256 + ((ds * 32 + hi * 16) ^ ((c & 7) << 4)));
                s0 = __builtin_amdgcn_mfma_f32_32x32x16_bf16(kf0, qf[ds], s0, 0, 0, 0);
            }
            if (do1) {
                #pragma unroll
                for (int ds = 0; ds < 8; ++ds) {
                    bf16x8 kf1 = *(const bf16x8*)(Klb + (32 + c) * 256 + ((ds * 32 + hi * 16) ^ ((c & 7) << 4)));
                    s1 = __builtin_amdgcn_mfma_f32_32x32x16_bf16(kf1, qf[ds], s1, 0, 0, 0);
                }
            }
            __builtin_amdgcn_s_setprio(0);

            float sv0[16], sv1[16];
            #pragma unroll
            for (int r = 0; r < 16; ++r) { sv0[r] = s0[r]; sv1[r] = do1 ? s1[r] : -1e30f; }

            if (diag0 || diag1) {
                #pragma unroll
                for (int r = 0; r < 16; ++r) {
                    int rr = (r & 3) + 8 * (r >> 2) + 4 * hi;
                    if (diag0) { if (rr > c) sv0[r] = -1e30f; }
                    else       { if (rr > c) sv1[r] = -1e30f; }
                }
            }

            float mx = -1e30f;
            #pragma unroll
            for (int r = 0; r < 16; ++r) mx = fmaxf(mx, fmaxf(sv0[r], sv1[r]));
            mx = redmax32(mx);

            if (__any(mx > m_run + 8.0f)) {
                float mnew = fmaxf(m_run, mx);
                float alpha = exp2f(m_run - mnew);
                m_run = mnew;
                l_run *= alpha;
                #pragma unroll
                for (int r = 0; r < 16; ++r) {
                    int qr = (r & 3) + 8 * (r >> 2) + 4 * hi;
                    float aR = __shfl(alpha, qr + (l & 32));
                    o0[r] *= aR; o1[r] *= aR; o2[r] *= aR; o3[r] *= aR;
                }
            }

            float e0[16], e1[16];
            float ls = 0.f;
            #pragma unroll
            for (int r = 0; r < 16; ++r) {
                e0[r] = exp2f(sv0[r] - m_run);
                e1[r] = exp2f(sv1[r] - m_run);
                ls += e0[r] + e1[r];
            }
            l_run += redsum32(ls);

            bf16x8 pa[4];
            #pragma unroll
            for (int ks = 0; ks < 4; ++ks) {
                const float* pe = (ks < 2) ? e0 : e1;
                const int b8 = (ks & 1) * 8;
                unsigned A  = pk2(pe[b8 + 0], pe[b8 + 1]);
                unsigned Bq = pk2(pe[b8 + 4], pe[b8 + 5]);
                unsigned C2 = pk2(pe[b8 + 2], pe[b8 + 3]);
                unsigned D2 = pk2(pe[b8 + 6], pe[b8 + 7]);
                pl32swap(A, Bq);
                pl32swap(C2, D2);
                union { uint4 u; bf16x8 v; } cv;
                cv.u.x = A;
                cv.u.y = C2;
                cv.u.z = Bq;
                cv.u.w = D2;
                pa[ks] = cv.v;
            }

            __builtin_amdgcn_s_setprio(1);
            #pragma unroll
            for (int ks = 0; ks < 4; ++ks) {
                if (ks >= 2 && !do1) continue;
                const int ko = (ks * 32 + hi * 16);
                bf16x8 vf;
                vf = *(const bf16x8*)(Vlb + (0 * 32 + c) * 128 + (ko ^ ((c & 7) << 4)));
                o0 = __builtin_amdgcn_mfma_f32_32x32x16_bf16(pa[ks], vf, o0, 0, 0, 0);
                vf = *(const bf16x8*)(Vlb + (1 * 32 + c) * 128 + (ko ^ ((c & 7) << 4)));
                o1 = __builtin_amdgcn_mfma_f32_32x32x16_bf16(pa[ks], vf, o1, 0, 0, 0);
                vf = *(const bf16x8*)(Vlb + (2 * 32 + c) * 128 + (ko ^ ((c & 7) << 4)));
                o2 = __builtin_amdgcn_mfma_f32_32x32x16_bf16(pa[ks], vf, o2, 0, 0, 0);
                vf = *(const bf16x8*)(Vlb + (3 * 32 + c) * 128 + (ko ^ ((c & 7) << 4)));
                o3 = __builtin_amdgcn_mfma_f32_32x32x16_bf16(pa[ks], vf, o3, 0, 0, 0);
            }
            __builtin_amdgcn_s_setprio(0);
        }
        __syncthreads();
    }

    const float linv = 1.0f / l_run;
    #pragma unroll
    for (int r = 0; r < 16; ++r) {
        int qr = (r & 3) + 8 * (r >> 2) + 4 * hi;
        float lr = __shfl(linv, qr + (l & 32));
        size_t base = ((size_t)(b * NS + q0 + qr)) * (NH * NHD) + h * NHD;
        Out[base + c]      = f2bf(o0[r] * lr);
        Out[base + 32 + c] = f2bf(o1[r] * lr);
        Out[base + 64 + c] = f2bf(o2[r] * lr);
        Out[base + 96 + c] = f2bf(o3[r] * lr);
    }
}

// ---------------- host launcher ----------------
extern "C" void kernel_launch(void* const* d_in, const int* in_sizes, int n_in,
                              void* d_out, int out_size, void* d_ws, size_t ws_size,
                              hipStream_t stream)
{
    (void)in_sizes; (void)n_in; (void)out_size; (void)ws_size;
    const float* hidden = (const float*)d_in[0];
    const float* cosb   = (const float*)d_in[1];
    const float* sinb   = (const float*)d_in[2];
    const float* qkv_w  = (const float*)d_in[3];
    const float* qkv_b  = (const float*)d_in[4];
    const float* o_w    = (const float*)d_in[5];
    float* out = (float*)d_out;

    char* ws = (char*)d_ws;
    size_t off = 0;
    auto alloc = [&](size_t bytes) {
        void* p = ws + off; off += (bytes + 255) & ~(size_t)255; return p;
    };
    u16* hid_bf  = (u16*)alloc((size_t)NB * NS * ND * 2);
    u16* qkvw_bf = (u16*)alloc((size_t)NQKV * ND * 2);
    u16* ow_bf   = (u16*)alloc((size_t)ND * NH * NHD * 2);
    u16* qkv     = (u16*)alloc((size_t)NB * NS * NQKV * 2);
    u16* Qb      = (u16*)alloc((size_t)NB * NH * NS * NHD * 2);
    u16* Kb      = (u16*)alloc((size_t)NB * NKH * NS * NHD * 2);
    u16* Vt      = (u16*)alloc((size_t)NB * NKH * NS * NHD * 2);
    u16* attn    = hid_bf;   // alias: hidden_bf16 dead after GEMM1

    int n1 = NB * NS * ND / 4;
    int n2 = NQKV * ND / 4;
    int n3 = ND * NH * NHD / 4;
    cvt_all<<<(n1 + n2 + n3 + 255) / 256, 256, 0, stream>>>(
        hidden, hid_bf, n1, qkv_w, qkvw_bf, n2, o_w, ow_bf, n3);

    int nwg1 = (NB * NS / 128) * (NQKV / 128);     // 640
    gemm_bt<1, 1><<<nwg1, 256, 0, stream>>>(hid_bf, qkvw_bf, qkv_b, qkv,
                                            NB * NS, NQKV, ND, NB * NS / 128, nwg1);

    int nr = NB * NS * NHD;                        // one thread per (bs, d)
    rope_scatter2<<<nr / 256, 256, 0, stream>>>(qkv, cosb, sinb, Qb, Kb, Vt);

    attn_fwd6<<<512, 256, 0, stream>>>(Qb, Kb, Vt, attn);

    int nwg2 = (NB * NS / 128) * (ND / 128);       // 512
    gemm_bt<0, 0><<<nwg2, 256, 0, stream>>>(attn, ow_bf, nullptr, out,
                                            NB * NS, ND, NH * NHD, NB * NS / 128, nwg2);
}

// Round 17
// 209.764 us; speedup vs baseline: 1.0526x; 1.0064x over previous
//
#include <hip/hip_runtime.h>

typedef unsigned short u16;
typedef __attribute__((ext_vector_type(8))) __bf16 bf16x8;
typedef __attribute__((ext_vector_type(2))) __bf16 bf16x2;
typedef __attribute__((ext_vector_type(4))) float f32x4;
typedef __attribute__((ext_vector_type(16))) float f32x16;
typedef __attribute__((ext_vector_type(2))) unsigned u32x2;

#define NB 2
#define NS 2048
#define ND 2048
#define NH 16
#define NKH 2
#define NHD 128
#define NQKV 2560
// 1/sqrt(128) * log2(e): scores in log2 domain -> exp2f = raw v_exp_f32
#define QSCALE (0.08838834764831845f * 1.4426950408889634f)

#define AS1 __attribute__((address_space(1)))
#define AS3 __attribute__((address_space(3)))

__device__ __forceinline__ u16 f2bf(float x) {
    union { float f; unsigned u; } v; v.f = x;
    unsigned r = v.u + 0x7fffu + ((v.u >> 16) & 1u);
    return (u16)(r >> 16);
}
__device__ __forceinline__ float bf2f(u16 x) {
    union { unsigned u; float f; } v; v.u = ((unsigned)x) << 16;
    return v.f;
}
__device__ __forceinline__ unsigned pk2(float lo, float hi_) {
    union { bf16x2 v; unsigned u; } t;
    t.v.x = (__bf16)lo; t.v.y = (__bf16)hi_;
    return t.u;
}
__device__ __forceinline__ void pl32swap(unsigned &a, unsigned &b) {
#if __has_builtin(__builtin_amdgcn_permlane32_swap)
    u32x2 r = __builtin_amdgcn_permlane32_swap(a, b, false, false);
    a = r.x; b = r.y;
#else
    asm volatile("v_permlane32_swap_b32 %0, %1" : "+v"(a), "+v"(b));
#endif
}
__device__ __forceinline__ float fbits(unsigned u) {
    union { unsigned u; float f; } v; v.u = u; return v.f;
}
__device__ __forceinline__ unsigned ubits(float f) {
    union { float f; unsigned u; } v; v.f = f; return v.u;
}
__device__ __forceinline__ float redmax32(float x) {
    unsigned a = ubits(x), b = a;
    pl32swap(a, b);
    return fmaxf(fbits(a), fbits(b));
}
__device__ __forceinline__ float redsum32(float x) {
    unsigned a = ubits(x), b = a;
    pl32swap(a, b);
    return fbits(a) + fbits(b);
}

// ---------------- fp32 -> bf16 conversion: all three inputs, one launch ----------------
__global__ void cvt_all(const float* __restrict__ a, u16* __restrict__ oa, int na,
                        const float* __restrict__ b, u16* __restrict__ ob, int nb,
                        const float* __restrict__ c, u16* __restrict__ oc, int nc)
{
    int i = blockIdx.x * 256 + threadIdx.x;
    const float* src; u16* dst;
    if (i < na)            { src = a; dst = oa; }
    else if (i < na + nb)  { src = b; dst = ob; i -= na; }
    else if (i < na + nb + nc) { src = c; dst = oc; i -= na + nb; }
    else return;
    float4 v = ((const float4*)src)[i];
    ushort4 o;
    o.x = f2bf(v.x); o.y = f2bf(v.y); o.z = f2bf(v.z); o.w = f2bf(v.w);
    ((ushort4*)dst)[i] = o;
}

// ---------------- GEMM: C[M,N] = A[M,K] * B[N,K]^T (+bias), XCD-swizzled 1D grid ----------------
template<int BIAS, int OUTBF16>
__global__ __launch_bounds__(256, 2)
void gemm_bt(const u16* __restrict__ A, const u16* __restrict__ B,
             const float* __restrict__ bias, void* __restrict__ Cout,
             int M, int N, int K, int mt, int nwg)
{
    __shared__ u16 lds[2][2][8192];
    const int l = threadIdx.x & 63;
    const int w = threadIdx.x >> 6;
    const int bid = blockIdx.x;
    const int wg = (bid & 7) * (nwg >> 3) + (bid >> 3);
    const int m0 = (wg % mt) * 128, n0 = (wg / mt) * 128;
    const int wm = (w >> 1) * 64, wn = (w & 1) * 64;
    f32x4 acc[4][4] = {};

    const int lbyte = ((l & 7) * 16) ^ ((l >> 3) << 4);

    auto stage = [&](int buf, int k0) {
        #pragma unroll
        for (int inst = 0; inst < 4; ++inst) {
            int row = inst * 32 + w * 8 + (l >> 3);
            const u16* sa = A + (size_t)(m0 + row) * K + k0 + (lbyte >> 1);
            const u16* sb = B + (size_t)(n0 + row) * K + k0 + (lbyte >> 1);
            __builtin_amdgcn_global_load_lds(
                (const AS1 void*)sa,
                (AS3 void*)&lds[buf][0][inst * 2048 + w * 512], 16, 0, 0);
            __builtin_amdgcn_global_load_lds(
                (const AS1 void*)sb,
                (AS3 void*)&lds[buf][1][inst * 2048 + w * 512], 16, 0, 0);
        }
    };

    auto compute = [&](int buf) {
        const char* Ab = (const char*)&lds[buf][0][0];
        const char* Bb = (const char*)&lds[buf][1][0];
        #pragma unroll
        for (int kk = 0; kk < 2; ++kk) {
            int ac2 = kk * 64 + (l >> 4) * 16;
            bf16x8 af[4], bfr[4];
            #pragma unroll
            for (int i = 0; i < 4; ++i) {
                int ar = wm + i * 16 + (l & 15);
                af[i] = *(const bf16x8*)(Ab + ar * 128 + (ac2 ^ ((ar & 7) << 4)));
                int br = wn + i * 16 + (l & 15);
                bfr[i] = *(const bf16x8*)(Bb + br * 128 + (ac2 ^ ((br & 7) << 4)));
            }
            #pragma unroll
            for (int i = 0; i < 4; ++i)
                #pragma unroll
                for (int j = 0; j < 4; ++j)
                    acc[i][j] = __builtin_amdgcn_mfma_f32_16x16x32_bf16(af[i], bfr[j], acc[i][j], 0, 0, 0);
        }
    };

    stage(0, 0);
    const int NT = K >> 6;
    for (int kt = 0; kt < NT; ++kt) {
        __syncthreads();
        if (kt + 1 < NT) stage((kt + 1) & 1, (kt + 1) << 6);
        compute(kt & 1);
    }

    #pragma unroll
    for (int j = 0; j < 4; ++j) {
        int col = n0 + wn + j * 16 + (l & 15);
        float bv = BIAS ? bias[col] : 0.0f;
        #pragma unroll
        for (int i = 0; i < 4; ++i) {
            int row = m0 + wm + i * 16 + (l >> 4) * 4;
            #pragma unroll
            for (int r = 0; r < 4; ++r) {
                float v = acc[i][j][r] + bv;
                if (OUTBF16)
                    ((u16*)Cout)[(size_t)(row + r) * N + col] = f2bf(v);
                else
                    ((float*)Cout)[(size_t)(row + r) * N + col] = v;
            }
        }
    }
}

// ---------------- RoPE + scatter, cos/sin-deduplicated ----------------
__global__ __launch_bounds__(256)
void rope_scatter2(const u16* __restrict__ qkv,
                   const float* __restrict__ cosb,
                   const float* __restrict__ sinb,
                   u16* __restrict__ Q, u16* __restrict__ Kb, u16* __restrict__ Vt)
{
    int n = blockIdx.x * 256 + threadIdx.x;       // [0, NB*NS*128)
    const int d = n & 127;
    const int bs = n >> 7;                        // b*NS + s
    const int b = bs >> 11, s = bs & 2047;

    const float cs = cosb[(size_t)bs * NHD + d];
    const float sn = sinb[(size_t)bs * NHD + d];
    const int pd = (d < 64) ? d + 64 : d - 64;
    const float psign = (d < 64) ? -1.0f : 1.0f;

    const u16* row = qkv + (size_t)bs * NQKV;

    #pragma unroll
    for (int h = 0; h < NH; ++h) {
        float x = bf2f(row[h * NHD + d]);
        float p = bf2f(row[h * NHD + pd]);
        float v = (x * cs + psign * p * sn) * QSCALE;
        Q[(((size_t)b * NH + h) * NS + s) * NHD + d] = f2bf(v);
    }
    #pragma unroll
    for (int kh = 0; kh < NKH; ++kh) {
        float x = bf2f(row[NH * NHD + kh * NHD + d]);
        float p = bf2f(row[NH * NHD + kh * NHD + pd]);
        float v = x * cs + psign * p * sn;
        Kb[(((size_t)b * NKH + kh) * NS + s) * NHD + d] = f2bf(v);
    }
    #pragma unroll
    for (int vh = 0; vh < NKH; ++vh) {
        Vt[(((size_t)b * NKH + vh) * NHD + d) * NS + s] = row[(NH + NKH) * NHD + vh * NHD + d];
    }
}

// ---------------- causal GQA flash attention v11: head-parallel waves ----------------
// 512 blocks x 4 waves. Block = (g, b, kh, pair): all 4 waves process the SAME
// 32 q-rows (g*32..+31) for 4 DIFFERENT q-heads (kh*8+pair*4+w) sharing the
// (b,kh) K/V stream. All waves have identical causal range NT = g/2+1 (64-kv
// tiles) -> 100% active wave-iterations (v6: 67%); staging drops 12544->8448
// tile-stages. LPT: g descending. bid&7 = (b,kh,pair) -> each XCD pins one
// 1 MB K/V stream in its L2. Inner loop byte-identical to v6.
__global__ __launch_bounds__(256, 2)
void attn_fwd11(const u16* __restrict__ Q, const u16* __restrict__ Kb,
                const u16* __restrict__ Vt, u16* __restrict__ Out)
{
    __shared__ u16 kl[2][8192];   // K tile: [64 rows][128 d] bf16, 16 KB per buf
    __shared__ u16 vl[2][8192];   // V tile: [128 d][64 kv] bf16, 16 KB per buf

    const int l = threadIdx.x & 63;
    const int w = threadIdx.x >> 6;
    const int bid = blockIdx.x;
    const int g = 63 - (bid >> 3);            // 0..63, longest blocks first
    const int rem = bid & 7;                  // (b, kh, pair)
    const int b = rem & 1;
    const int kh = (rem >> 1) & 1;
    const int h = kh * 8 + ((rem >> 2) & 1) * 4 + w;   // this wave's q-head
    const int c = l & 31, hi = l >> 5;
    const int q0 = g * 32;                    // all 4 waves: same 32 q-rows
    const int qend = q0 + 31;

    const u16* Qp = Q + (((size_t)b * NH + h) * NS + q0) * NHD;
    const u16* Kp = Kb + ((size_t)b * NKH + kh) * NS * NHD;
    const u16* Vp = Vt + ((size_t)b * NKH + kh) * (size_t)NHD * NS;

    bf16x8 qf[8];
    #pragma unroll
    for (int ds = 0; ds < 8; ++ds)
        qf[ds] = *(const bf16x8*)(Qp + c * NHD + ds * 16 + hi * 8);

    f32x16 o0 = {}, o1 = {}, o2 = {}, o3 = {};
    float m_run = -1e30f, l_run = 0.f;

    auto stage = [&](int buf, int kt) {
        const int kb = kt << 6;
        #pragma unroll
        for (int ii = 0; ii < 4; ++ii) {           // K: rows r, swizzled col chunks
            int r = w * 16 + ii * 4 + (l >> 4);
            int q = (l & 15) ^ ((ii * 4 + (l >> 4)) & 7);
            const u16* src = Kp + (size_t)(kb + r) * NHD + q * 8;
            __builtin_amdgcn_global_load_lds(
                (const AS1 void*)src,
                (AS3 void*)&kl[buf][(w * 4 + ii) * 512], 16, 0, 0);
        }
        #pragma unroll
        for (int ii = 0; ii < 4; ++ii) {           // V: rows d, swizzled kv chunks
            int jj = w * 4 + ii;
            int d = jj * 8 + (l >> 3);
            int q = (l & 7) ^ ((l >> 3) & 7);
            const u16* src = Vp + (size_t)d * NS + kb + q * 8;
            __builtin_amdgcn_global_load_lds(
                (const AS1 void*)src,
                (AS3 void*)&vl[buf][jj * 512], 16, 0, 0);
        }
    };

    const int NT = (g >> 1) + 1;               // exact causal range, 64-kv tiles
    stage(0, 0);
    __syncthreads();

    for (int kt = 0; kt < NT; ++kt) {
        const int kb = kt << 6;
        const int cur = kt & 1;
        if (kt + 1 < NT) stage(cur ^ 1, kt + 1);

        const bool do1 = (kb + 32 <= qend);
        {
            const bool diag0 = (kb == q0);
            const bool diag1 = (kb + 32 == q0);
            const char* Klb = (const char*)kl[cur];
            const char* Vlb = (const char*)vl[cur];

            f32x16 s0 = {}, s1 = {};
            __builtin_amdgcn_s_setprio(1);
            #pragma unroll
            for (int ds = 0; ds < 8; ++ds) {
                bf16x8 kf0 = *(const bf16x8*)(Klb + c * 256 + ((ds * 32 + hi * 16) ^ ((c & 7) << 4)));
                s0 = __builtin_amdgcn_mfma_f32_32x32x16_bf16(kf0, qf[ds], s0, 0, 0, 0);
            }
            if (do1) {
                #pragma unroll
                for (int ds = 0; ds < 8; ++ds) {
                    bf16x8 kf1 = *(const bf16x8*)(Klb + (32 + c) * 256 + ((ds * 32 + hi * 16) ^ ((c & 7) << 4)));
                    s1 = __builtin_amdgcn_mfma_f32_32x32x16_bf16(kf1, qf[ds], s1, 0, 0, 0);
                }
            }
            __builtin_amdgcn_s_setprio(0);

            float sv0[16], sv1[16];
            #pragma unroll
            for (int r = 0; r < 16; ++r) { sv0[r] = s0[r]; sv1[r] = do1 ? s1[r] : -1e30f; }

            if (diag0 || diag1) {
                #pragma unroll
                for (int r = 0; r < 16; ++r) {
                    int rr = (r & 3) + 8 * (r >> 2) + 4 * hi;
                    if (diag0) { if (rr > c) sv0[r] = -1e30f; }
                    else       { if (rr > c) sv1[r] = -1e30f; }
                }
            }

            float mx = -1e30f;
            #pragma unroll
            for (int r = 0; r < 16; ++r) mx = fmaxf(mx, fmaxf(sv0[r], sv1[r]));
            mx = redmax32(mx);

            if (__any(mx > m_run + 8.0f)) {
                float mnew = fmaxf(m_run, mx);
                float alpha = exp2f(m_run - mnew);
                m_run = mnew;
                l_run *= alpha;
                #pragma unroll
                for (int r = 0; r < 16; ++r) {
                    int qr = (r & 3) + 8 * (r >> 2) + 4 * hi;
                    float aR = __shfl(alpha, qr + (l & 32));
                    o0[r] *= aR; o1[r] *= aR; o2[r] *= aR; o3[r] *= aR;
                }
            }

            float e0[16], e1[16];
            float ls = 0.f;
            #pragma unroll
            for (int r = 0; r < 16; ++r) {
                e0[r] = exp2f(sv0[r] - m_run);
                e1[r] = exp2f(sv1[r] - m_run);
                ls += e0[r] + e1[r];
            }
            l_run += redsum32(ls);

            bf16x8 pa[4];
            #pragma unroll
            for (int ks = 0; ks < 4; ++ks) {
                const float* pe = (ks < 2) ? e0 : e1;
                const int b8 = (ks & 1) * 8;
                unsigned A  = pk2(pe[b8 + 0], pe[b8 + 1]);
                unsigned Bq = pk2(pe[b8 + 4], pe[b8 + 5]);
                unsigned C2 = pk2(pe[b8 + 2], pe[b8 + 3]);
                unsigned D2 = pk2(pe[b8 + 6], pe[b8 + 7]);
                pl32swap(A, Bq);
                pl32swap(C2, D2);
                union { uint4 u; bf16x8 v; } cv;
                cv.u.x = A;
                cv.u.y = C2;
                cv.u.z = Bq;
                cv.u.w = D2;
                pa[ks] = cv.v;
            }

            __builtin_amdgcn_s_setprio(1);
            #pragma unroll
            for (int ks = 0; ks < 4; ++ks) {
                if (ks >= 2 && !do1) continue;
                const int ko = (ks * 32 + hi * 16);
                bf16x8 vf;
                vf = *(const bf16x8*)(Vlb + (0 * 32 + c) * 128 + (ko ^ ((c & 7) << 4)));
                o0 = __builtin_amdgcn_mfma_f32_32x32x16_bf16(pa[ks], vf, o0, 0, 0, 0);
                vf = *(const bf16x8*)(Vlb + (1 * 32 + c) * 128 + (ko ^ ((c & 7) << 4)));
                o1 = __builtin_amdgcn_mfma_f32_32x32x16_bf16(pa[ks], vf, o1, 0, 0, 0);
                vf = *(const bf16x8*)(Vlb + (2 * 32 + c) * 128 + (ko ^ ((c & 7) << 4)));
                o2 = __builtin_amdgcn_mfma_f32_32x32x16_bf16(pa[ks], vf, o2, 0, 0, 0);
                vf = *(const bf16x8*)(Vlb + (3 * 32 + c) * 128 + (ko ^ ((c & 7) << 4)));
                o3 = __builtin_amdgcn_mfma_f32_32x32x16_bf16(pa[ks], vf, o3, 0, 0, 0);
            }
            __builtin_amdgcn_s_setprio(0);
        }
        __syncthreads();
    }

    const float linv = 1.0f / l_run;
    #pragma unroll
    for (int r = 0; r < 16; ++r) {
        int qr = (r & 3) + 8 * (r >> 2) + 4 * hi;
        float lr = __shfl(linv, qr + (l & 32));
        size_t base = ((size_t)(b * NS + q0 + qr)) * (NH * NHD) + h * NHD;
        Out[base + c]      = f2bf(o0[r] * lr);
        Out[base + 32 + c] = f2bf(o1[r] * lr);
        Out[base + 64 + c] = f2bf(o2[r] * lr);
        Out[base + 96 + c] = f2bf(o3[r] * lr);
    }
}

// ---------------- host launcher ----------------
extern "C" void kernel_launch(void* const* d_in, const int* in_sizes, int n_in,
                              void* d_out, int out_size, void* d_ws, size_t ws_size,
                              hipStream_t stream)
{
    (void)in_sizes; (void)n_in; (void)out_size; (void)ws_size;
    const float* hidden = (const float*)d_in[0];
    const float* cosb   = (const float*)d_in[1];
    const float* sinb   = (const float*)d_in[2];
    const float* qkv_w  = (const float*)d_in[3];
    const float* qkv_b  = (const float*)d_in[4];
    const float* o_w    = (const float*)d_in[5];
    float* out = (float*)d_out;

    char* ws = (char*)d_ws;
    size_t off = 0;
    auto alloc = [&](size_t bytes) {
        void* p = ws + off; off += (bytes + 255) & ~(size_t)255; return p;
    };
    u16* hid_bf  = (u16*)alloc((size_t)NB * NS * ND * 2);
    u16* qkvw_bf = (u16*)alloc((size_t)NQKV * ND * 2);
    u16* ow_bf   = (u16*)alloc((size_t)ND * NH * NHD * 2);
    u16* qkv     = (u16*)alloc((size_t)NB * NS * NQKV * 2);
    u16* Qb      = (u16*)alloc((size_t)NB * NH * NS * NHD * 2);
    u16* Kb      = (u16*)alloc((size_t)NB * NKH * NS * NHD * 2);
    u16* Vt      = (u16*)alloc((size_t)NB * NKH * NS * NHD * 2);
    u16* attn    = hid_bf;   // alias: hidden_bf16 dead after GEMM1

    int n1 = NB * NS * ND / 4;
    int n2 = NQKV * ND / 4;
    int n3 = ND * NH * NHD / 4;
    cvt_all<<<(n1 + n2 + n3 + 255) / 256, 256, 0, stream>>>(
        hidden, hid_bf, n1, qkv_w, qkvw_bf, n2, o_w, ow_bf, n3);

    int nwg1 = (NB * NS / 128) * (NQKV / 128);     // 640
    gemm_bt<1, 1><<<nwg1, 256, 0, stream>>>(hid_bf, qkvw_bf, qkv_b, qkv,
                                            NB * NS, NQKV, ND, NB * NS / 128, nwg1);

    int nr = NB * NS * NHD;                        // one thread per (bs, d)
    rope_scatter2<<<nr / 256, 256, 0, stream>>>(qkv, cosb, sinb, Qb, Kb, Vt);

    attn_fwd11<<<512, 256, 0, stream>>>(Qb, Kb, Vt, attn);

    int nwg2 = (NB * NS / 128) * (ND / 128);       // 512
    gemm_bt<0, 0><<<nwg2, 256, 0, stream>>>(attn, ow_bf, nullptr, out,
                                            NB * NS, ND, NH * NHD, NB * NS / 128, nwg2);
}

// Round 18
// 209.357 us; speedup vs baseline: 1.0546x; 1.0019x over previous
//
#include <hip/hip_runtime.h>

typedef unsigned short u16;
typedef __attribute__((ext_vector_type(8))) __bf16 bf16x8;
typedef __attribute__((ext_vector_type(2))) __bf16 bf16x2;
typedef __attribute__((ext_vector_type(4))) float f32x4;
typedef __attribute__((ext_vector_type(16))) float f32x16;
typedef __attribute__((ext_vector_type(2))) unsigned u32x2;

#define NB 2
#define NS 2048
#define ND 2048
#define NH 16
#define NKH 2
#define NHD 128
#define NQKV 2560
// 1/sqrt(128) * log2(e): scores in log2 domain -> exp2f = raw v_exp_f32
#define QSCALE (0.08838834764831845f * 1.4426950408889634f)

#define AS1 __attribute__((address_space(1)))
#define AS3 __attribute__((address_space(3)))

__device__ __forceinline__ u16 f2bf(float x) {
    union { float f; unsigned u; } v; v.f = x;
    unsigned r = v.u + 0x7fffu + ((v.u >> 16) & 1u);
    return (u16)(r >> 16);
}
__device__ __forceinline__ float bf2f(u16 x) {
    union { unsigned u; float f; } v; v.u = ((unsigned)x) << 16;
    return v.f;
}
__device__ __forceinline__ unsigned pk2(float lo, float hi_) {
    union { bf16x2 v; unsigned u; } t;
    t.v.x = (__bf16)lo; t.v.y = (__bf16)hi_;
    return t.u;
}
__device__ __forceinline__ void pl32swap(unsigned &a, unsigned &b) {
#if __has_builtin(__builtin_amdgcn_permlane32_swap)
    u32x2 r = __builtin_amdgcn_permlane32_swap(a, b, false, false);
    a = r.x; b = r.y;
#else
    asm volatile("v_permlane32_swap_b32 %0, %1" : "+v"(a), "+v"(b));
#endif
}
__device__ __forceinline__ float fbits(unsigned u) {
    union { unsigned u; float f; } v; v.u = u; return v.f;
}
__device__ __forceinline__ unsigned ubits(float f) {
    union { float f; unsigned u; } v; v.f = f; return v.u;
}
__device__ __forceinline__ float redmax32(float x) {
    unsigned a = ubits(x), b = a;
    pl32swap(a, b);
    return fmaxf(fbits(a), fbits(b));
}
__device__ __forceinline__ float redsum32(float x) {
    unsigned a = ubits(x), b = a;
    pl32swap(a, b);
    return fbits(a) + fbits(b);
}

// ---------------- fp32 -> bf16 conversion: all three inputs, one launch ----------------
__global__ void cvt_all(const float* __restrict__ a, u16* __restrict__ oa, int na,
                        const float* __restrict__ b, u16* __restrict__ ob, int nb,
                        const float* __restrict__ c, u16* __restrict__ oc, int nc)
{
    int i = blockIdx.x * 256 + threadIdx.x;
    const float* src; u16* dst;
    if (i < na)            { src = a; dst = oa; }
    else if (i < na + nb)  { src = b; dst = ob; i -= na; }
    else if (i < na + nb + nc) { src = c; dst = oc; i -= na + nb; }
    else return;
    float4 v = ((const float4*)src)[i];
    ushort4 o;
    o.x = f2bf(v.x); o.y = f2bf(v.y); o.z = f2bf(v.z); o.w = f2bf(v.w);
    ((ushort4*)dst)[i] = o;
}

// ---------------- GEMM: C[M,N] = A[M,K] * B[N,K]^T (+bias), XCD-swizzled 1D grid ----------------
template<int BIAS, int OUTBF16>
__global__ __launch_bounds__(256, 2)
void gemm_bt(const u16* __restrict__ A, const u16* __restrict__ B,
             const float* __restrict__ bias, void* __restrict__ Cout,
             int M, int N, int K, int mt, int nwg)
{
    __shared__ u16 lds[2][2][8192];
    const int l = threadIdx.x & 63;
    const int w = threadIdx.x >> 6;
    const int bid = blockIdx.x;
    const int wg = (bid & 7) * (nwg >> 3) + (bid >> 3);
    const int m0 = (wg % mt) * 128, n0 = (wg / mt) * 128;
    const int wm = (w >> 1) * 64, wn = (w & 1) * 64;
    f32x4 acc[4][4] = {};

    const int lbyte = ((l & 7) * 16) ^ ((l >> 3) << 4);

    auto stage = [&](int buf, int k0) {
        #pragma unroll
        for (int inst = 0; inst < 4; ++inst) {
            int row = inst * 32 + w * 8 + (l >> 3);
            const u16* sa = A + (size_t)(m0 + row) * K + k0 + (lbyte >> 1);
            const u16* sb = B + (size_t)(n0 + row) * K + k0 + (lbyte >> 1);
            __builtin_amdgcn_global_load_lds(
                (const AS1 void*)sa,
                (AS3 void*)&lds[buf][0][inst * 2048 + w * 512], 16, 0, 0);
            __builtin_amdgcn_global_load_lds(
                (const AS1 void*)sb,
                (AS3 void*)&lds[buf][1][inst * 2048 + w * 512], 16, 0, 0);
        }
    };

    auto compute = [&](int buf) {
        const char* Ab = (const char*)&lds[buf][0][0];
        const char* Bb = (const char*)&lds[buf][1][0];
        #pragma unroll
        for (int kk = 0; kk < 2; ++kk) {
            int ac2 = kk * 64 + (l >> 4) * 16;
            bf16x8 af[4], bfr[4];
            #pragma unroll
            for (int i = 0; i < 4; ++i) {
                int ar = wm + i * 16 + (l & 15);
                af[i] = *(const bf16x8*)(Ab + ar * 128 + (ac2 ^ ((ar & 7) << 4)));
                int br = wn + i * 16 + (l & 15);
                bfr[i] = *(const bf16x8*)(Bb + br * 128 + (ac2 ^ ((br & 7) << 4)));
            }
            #pragma unroll
            for (int i = 0; i < 4; ++i)
                #pragma unroll
                for (int j = 0; j < 4; ++j)
                    acc[i][j] = __builtin_amdgcn_mfma_f32_16x16x32_bf16(af[i], bfr[j], acc[i][j], 0, 0, 0);
        }
    };

    stage(0, 0);
    const int NT = K >> 6;
    for (int kt = 0; kt < NT; ++kt) {
        __syncthreads();
        if (kt + 1 < NT) stage((kt + 1) & 1, (kt + 1) << 6);
        compute(kt & 1);
    }

    #pragma unroll
    for (int j = 0; j < 4; ++j) {
        int col = n0 + wn + j * 16 + (l & 15);
        float bv = BIAS ? bias[col] : 0.0f;
        #pragma unroll
        for (int i = 0; i < 4; ++i) {
            int row = m0 + wm + i * 16 + (l >> 4) * 4;
            #pragma unroll
            for (int r = 0; r < 4; ++r) {
                float v = acc[i][j][r] + bv;
                if (OUTBF16)
                    ((u16*)Cout)[(size_t)(row + r) * N + col] = f2bf(v);
                else
                    ((float*)Cout)[(size_t)(row + r) * N + col] = v;
            }
        }
    }
}

// ---------------- RoPE + scatter, cos/sin-deduplicated ----------------
__global__ __launch_bounds__(256)
void rope_scatter2(const u16* __restrict__ qkv,
                   const float* __restrict__ cosb,
                   const float* __restrict__ sinb,
                   u16* __restrict__ Q, u16* __restrict__ Kb, u16* __restrict__ Vt)
{
    int n = blockIdx.x * 256 + threadIdx.x;       // [0, NB*NS*128)
    const int d = n & 127;
    const int bs = n >> 7;                        // b*NS + s
    const int b = bs >> 11, s = bs & 2047;

    const float cs = cosb[(size_t)bs * NHD + d];
    const float sn = sinb[(size_t)bs * NHD + d];
    const int pd = (d < 64) ? d + 64 : d - 64;
    const float psign = (d < 64) ? -1.0f : 1.0f;

    const u16* row = qkv + (size_t)bs * NQKV;

    #pragma unroll
    for (int h = 0; h < NH; ++h) {
        float x = bf2f(row[h * NHD + d]);
        float p = bf2f(row[h * NHD + pd]);
        float v = (x * cs + psign * p * sn) * QSCALE;
        Q[(((size_t)b * NH + h) * NS + s) * NHD + d] = f2bf(v);
    }
    #pragma unroll
    for (int kh = 0; kh < NKH; ++kh) {
        float x = bf2f(row[NH * NHD + kh * NHD + d]);
        float p = bf2f(row[NH * NHD + kh * NHD + pd]);
        float v = x * cs + psign * p * sn;
        Kb[(((size_t)b * NKH + kh) * NS + s) * NHD + d] = f2bf(v);
    }
    #pragma unroll
    for (int vh = 0; vh < NKH; ++vh) {
        Vt[(((size_t)b * NKH + vh) * NHD + d) * NS + s] = row[(NH + NKH) * NHD + vh * NHD + d];
    }
}

// ---------------- causal GQA flash attention v12: balanced co-resident pairs ----------------
// Same as v11 (head-parallel waves, 100% active iterations) but the bid->g map
// pairs g with 63-g on co-resident blocks (i, i+256): per-CU tile total is
// uniformly 33 (v11: 18..48, makespan-bound at 48).
__global__ __launch_bounds__(256, 2)
void attn_fwd12(const u16* __restrict__ Q, const u16* __restrict__ Kb,
                const u16* __restrict__ Vt, u16* __restrict__ Out)
{
    __shared__ u16 kl[2][8192];   // K tile: [64 rows][128 d] bf16, 16 KB per buf
    __shared__ u16 vl[2][8192];   // V tile: [128 d][64 kv] bf16, 16 KB per buf

    const int l = threadIdx.x & 63;
    const int w = threadIdx.x >> 6;
    const int bid = blockIdx.x;
    const int gi = bid >> 3;
    const int g = (gi < 32) ? (63 - gi) : (gi - 32);   // sweep1: 63..32, sweep2: 0..31
    const int rem = bid & 7;                  // (b, kh, pair)
    const int b = rem & 1;
    const int kh = (rem >> 1) & 1;
    const int h = kh * 8 + ((rem >> 2) & 1) * 4 + w;   // this wave's q-head
    const int c = l & 31, hi = l >> 5;
    const int q0 = g * 32;                    // all 4 waves: same 32 q-rows
    const int qend = q0 + 31;

    const u16* Qp = Q + (((size_t)b * NH + h) * NS + q0) * NHD;
    const u16* Kp = Kb + ((size_t)b * NKH + kh) * NS * NHD;
    const u16* Vp = Vt + ((size_t)b * NKH + kh) * (size_t)NHD * NS;

    bf16x8 qf[8];
    #pragma unroll
    for (int ds = 0; ds < 8; ++ds)
        qf[ds] = *(const bf16x8*)(Qp + c * NHD + ds * 16 + hi * 8);

    f32x16 o0 = {}, o1 = {}, o2 = {}, o3 = {};
    float m_run = -1e30f, l_run = 0.f;

    auto stage = [&](int buf, int kt) {
        const int kb = kt << 6;
        #pragma unroll
        for (int ii = 0; ii < 4; ++ii) {           // K: rows r, swizzled col chunks
            int r = w * 16 + ii * 4 + (l >> 4);
            int q = (l & 15) ^ ((ii * 4 + (l >> 4)) & 7);
            const u16* src = Kp + (size_t)(kb + r) * NHD + q * 8;
            __builtin_amdgcn_global_load_lds(
                (const AS1 void*)src,
                (AS3 void*)&kl[buf][(w * 4 + ii) * 512], 16, 0, 0);
        }
        #pragma unroll
        for (int ii = 0; ii < 4; ++ii) {           // V: rows d, swizzled kv chunks
            int jj = w * 4 + ii;
            int d = jj * 8 + (l >> 3);
            int q = (l & 7) ^ ((l >> 3) & 7);
            const u16* src = Vp + (size_t)d * NS + kb + q * 8;
            __builtin_amdgcn_global_load_lds(
                (const AS1 void*)src,
                (AS3 void*)&vl[buf][jj * 512], 16, 0, 0);
        }
    };

    const int NT = (g >> 1) + 1;               // exact causal range, 64-kv tiles
    stage(0, 0);
    __syncthreads();

    for (int kt = 0; kt < NT; ++kt) {
        const int kb = kt << 6;
        const int cur = kt & 1;
        if (kt + 1 < NT) stage(cur ^ 1, kt + 1);

        const bool do1 = (kb + 32 <= qend);
        {
            const bool diag0 = (kb == q0);
            const bool diag1 = (kb + 32 == q0);
            const char* Klb = (const char*)kl[cur];
            const char* Vlb = (const char*)vl[cur];

            f32x16 s0 = {}, s1 = {};
            __builtin_amdgcn_s_setprio(1);
            #pragma unroll
            for (int ds = 0; ds < 8; ++ds) {
                bf16x8 kf0 = *(const bf16x8*)(Klb + c * 256 + ((ds * 32 + hi * 16) ^ ((c & 7) << 4)));
                s0 = __builtin_amdgcn_mfma_f32_32x32x16_bf16(kf0, qf[ds], s0, 0, 0, 0);
            }
            if (do1) {
                #pragma unroll
                for (int ds = 0; ds < 8; ++ds) {
                    bf16x8 kf1 = *(const bf16x8*)(Klb + (32 + c) * 256 + ((ds * 32 + hi * 16) ^ ((c & 7) << 4)));
                    s1 = __builtin_amdgcn_mfma_f32_32x32x16_bf16(kf1, qf[ds], s1, 0, 0, 0);
                }
            }
            __builtin_amdgcn_s_setprio(0);

            float sv0[16], sv1[16];
            #pragma unroll
            for (int r = 0; r < 16; ++r) { sv0[r] = s0[r]; sv1[r] = do1 ? s1[r] : -1e30f; }

            if (diag0 || diag1) {
                #pragma unroll
                for (int r = 0; r < 16; ++r) {
                    int rr = (r & 3) + 8 * (r >> 2) + 4 * hi;
                    if (diag0) { if (rr > c) sv0[r] = -1e30f; }
                    else       { if (rr > c) sv1[r] = -1e30f; }
                }
            }

            float mx = -1e30f;
            #pragma unroll
            for (int r = 0; r < 16; ++r) mx = fmaxf(mx, fmaxf(sv0[r], sv1[r]));
            mx = redmax32(mx);

            if (__any(mx > m_run + 8.0f)) {
                float mnew = fmaxf(m_run, mx);
                float alpha = exp2f(m_run - mnew);
                m_run = mnew;
                l_run *= alpha;
                #pragma unroll
                for (int r = 0; r < 16; ++r) {
                    int qr = (r & 3) + 8 * (r >> 2) + 4 * hi;
                    float aR = __shfl(alpha, qr + (l & 32));
                    o0[r] *= aR; o1[r] *= aR; o2[r] *= aR; o3[r] *= aR;
                }
            }

            float e0[16], e1[16];
            float ls = 0.f;
            #pragma unroll
            for (int r = 0; r < 16; ++r) {
                e0[r] = exp2f(sv0[r] - m_run);
                e1[r] = exp2f(sv1[r] - m_run);
                ls += e0[r] + e1[r];
            }
            l_run += redsum32(ls);

            bf16x8 pa[4];
            #pragma unroll
            for (int ks = 0; ks < 4; ++ks) {
                const float* pe = (ks < 2) ? e0 : e1;
                const int b8 = (ks & 1) * 8;
                unsigned A  = pk2(pe[b8 + 0], pe[b8 + 1]);
                unsigned Bq = pk2(pe[b8 + 4], pe[b8 + 5]);
                unsigned C2 = pk2(pe[b8 + 2], pe[b8 + 3]);
                unsigned D2 = pk2(pe[b8 + 6], pe[b8 + 7]);
                pl32swap(A, Bq);
                pl32swap(C2, D2);
                union { uint4 u; bf16x8 v; } cv;
                cv.u.x = A;
                cv.u.y = C2;
                cv.u.z = Bq;
                cv.u.w = D2;
                pa[ks] = cv.v;
            }

            __builtin_amdgcn_s_setprio(1);
            #pragma unroll
            for (int ks = 0; ks < 4; ++ks) {
                if (ks >= 2 && !do1) continue;
                const int ko = (ks * 32 + hi * 16);
                bf16x8 vf;
                vf = *(const bf16x8*)(Vlb + (0 * 32 + c) * 128 + (ko ^ ((c & 7) << 4)));
                o0 = __builtin_amdgcn_mfma_f32_32x32x16_bf16(pa[ks], vf, o0, 0, 0, 0);
                vf = *(const bf16x8*)(Vlb + (1 * 32 + c) * 128 + (ko ^ ((c & 7) << 4)));
                o1 = __builtin_amdgcn_mfma_f32_32x32x16_bf16(pa[ks], vf, o1, 0, 0, 0);
                vf = *(const bf16x8*)(Vlb + (2 * 32 + c) * 128 + (ko ^ ((c & 7) << 4)));
                o2 = __builtin_amdgcn_mfma_f32_32x32x16_bf16(pa[ks], vf, o2, 0, 0, 0);
                vf = *(const bf16x8*)(Vlb + (3 * 32 + c) * 128 + (ko ^ ((c & 7) << 4)));
                o3 = __builtin_amdgcn_mfma_f32_32x32x16_bf16(pa[ks], vf, o3, 0, 0, 0);
            }
            __builtin_amdgcn_s_setprio(0);
        }
        __syncthreads();
    }

    const float linv = 1.0f / l_run;
    #pragma unroll
    for (int r = 0; r < 16; ++r) {
        int qr = (r & 3) + 8 * (r >> 2) + 4 * hi;
        float lr = __shfl(linv, qr + (l & 32));
        size_t base = ((size_t)(b * NS + q0 + qr)) * (NH * NHD) + h * NHD;
        Out[base + c]      = f2bf(o0[r] * lr);
        Out[base + 32 + c] = f2bf(o1[r] * lr);
        Out[base + 64 + c] = f2bf(o2[r] * lr);
        Out[base + 96 + c] = f2bf(o3[r] * lr);
    }
}

// ---------------- host launcher ----------------
extern "C" void kernel_launch(void* const* d_in, const int* in_sizes, int n_in,
                              void* d_out, int out_size, void* d_ws, size_t ws_size,
                              hipStream_t stream)
{
    (void)in_sizes; (void)n_in; (void)out_size; (void)ws_size;
    const float* hidden = (const float*)d_in[0];
    const float* cosb   = (const float*)d_in[1];
    const float* sinb   = (const float*)d_in[2];
    const float* qkv_w  = (const float*)d_in[3];
    const float* qkv_b  = (const float*)d_in[4];
    const float* o_w    = (const float*)d_in[5];
    float* out = (float*)d_out;

    char* ws = (char*)d_ws;
    size_t off = 0;
    auto alloc = [&](size_t bytes) {
        void* p = ws + off; off += (bytes + 255) & ~(size_t)255; return p;
    };
    u16* hid_bf  = (u16*)alloc((size_t)NB * NS * ND * 2);
    u16* qkvw_bf = (u16*)alloc((size_t)NQKV * ND * 2);
    u16* ow_bf   = (u16*)alloc((size_t)ND * NH * NHD * 2);
    u16* qkv     = (u16*)alloc((size_t)NB * NS * NQKV * 2);
    u16* Qb      = (u16*)alloc((size_t)NB * NH * NS * NHD * 2);
    u16* Kb      = (u16*)alloc((size_t)NB * NKH * NS * NHD * 2);
    u16* Vt      = (u16*)alloc((size_t)NB * NKH * NS * NHD * 2);
    u16* attn    = hid_bf;   // alias: hidden_bf16 dead after GEMM1

    int n1 = NB * NS * ND / 4;
    int n2 = NQKV * ND / 4;
    int n3 = ND * NH * NHD / 4;
    cvt_all<<<(n1 + n2 + n3 + 255) / 256, 256, 0, stream>>>(
        hidden, hid_bf, n1, qkv_w, qkvw_bf, n2, o_w, ow_bf, n3);

    int nwg1 = (NB * NS / 128) * (NQKV / 128);     // 640
    gemm_bt<1, 1><<<nwg1, 256, 0, stream>>>(hid_bf, qkvw_bf, qkv_b, qkv,
                                            NB * NS, NQKV, ND, NB * NS / 128, nwg1);

    int nr = NB * NS * NHD;                        // one thread per (bs, d)
    rope_scatter2<<<nr / 256, 256, 0, stream>>>(qkv, cosb, sinb, Qb, Kb, Vt);

    attn_fwd12<<<512, 256, 0, stream>>>(Qb, Kb, Vt, attn);

    int nwg2 = (NB * NS / 128) * (ND / 128);       // 512
    gemm_bt<0, 0><<<nwg2, 256, 0, stream>>>(attn, ow_bf, nullptr, out,
                                            NB * NS, ND, NH * NHD, NB * NS / 128, nwg2);
}

// Round 19
// 202.829 us; speedup vs baseline: 1.0885x; 1.0322x over previous
//
#include <hip/hip_runtime.h>

typedef unsigned short u16;
typedef __attribute__((ext_vector_type(8))) __bf16 bf16x8;
typedef __attribute__((ext_vector_type(2))) __bf16 bf16x2;
typedef __attribute__((ext_vector_type(4))) float f32x4;
typedef __attribute__((ext_vector_type(16))) float f32x16;
typedef __attribute__((ext_vector_type(2))) unsigned u32x2;

#define NB 2
#define NS 2048
#define ND 2048
#define NH 16
#define NKH 2
#define NHD 128
#define NQKV 2560
// 1/sqrt(128) * log2(e): scores in log2 domain -> exp2f = raw v_exp_f32
#define QSCALE (0.08838834764831845f * 1.4426950408889634f)

#define AS1 __attribute__((address_space(1)))
#define AS3 __attribute__((address_space(3)))

__device__ __forceinline__ u16 f2bf(float x) {
    union { float f; unsigned u; } v; v.f = x;
    unsigned r = v.u + 0x7fffu + ((v.u >> 16) & 1u);
    return (u16)(r >> 16);
}
__device__ __forceinline__ float bf2f(u16 x) {
    union { unsigned u; float f; } v; v.u = ((unsigned)x) << 16;
    return v.f;
}
__device__ __forceinline__ unsigned pk2(float lo, float hi_) {
    union { bf16x2 v; unsigned u; } t;
    t.v.x = (__bf16)lo; t.v.y = (__bf16)hi_;
    return t.u;
}
__device__ __forceinline__ void pl32swap(unsigned &a, unsigned &b) {
#if __has_builtin(__builtin_amdgcn_permlane32_swap)
    u32x2 r = __builtin_amdgcn_permlane32_swap(a, b, false, false);
    a = r.x; b = r.y;
#else
    asm volatile("v_permlane32_swap_b32 %0, %1" : "+v"(a), "+v"(b));
#endif
}
__device__ __forceinline__ float fbits(unsigned u) {
    union { unsigned u; float f; } v; v.u = u; return v.f;
}
__device__ __forceinline__ unsigned ubits(float f) {
    union { float f; unsigned u; } v; v.f = f; return v.u;
}
__device__ __forceinline__ float redmax32(float x) {
    unsigned a = ubits(x), b = a;
    pl32swap(a, b);
    return fmaxf(fbits(a), fbits(b));
}
__device__ __forceinline__ float redsum32(float x) {
    unsigned a = ubits(x), b = a;
    pl32swap(a, b);
    return fbits(a) + fbits(b);
}

// ---------------- fp32 -> bf16 conversion: all three inputs, one launch ----------------
__global__ void cvt_all(const float* __restrict__ a, u16* __restrict__ oa, int na,
                        const float* __restrict__ b, u16* __restrict__ ob, int nb,
                        const float* __restrict__ c, u16* __restrict__ oc, int nc)
{
    int i = blockIdx.x * 256 + threadIdx.x;
    const float* src; u16* dst;
    if (i < na)            { src = a; dst = oa; }
    else if (i < na + nb)  { src = b; dst = ob; i -= na; }
    else if (i < na + nb + nc) { src = c; dst = oc; i -= na + nb; }
    else return;
    float4 v = ((const float4*)src)[i];
    ushort4 o;
    o.x = f2bf(v.x); o.y = f2bf(v.y); o.z = f2bf(v.z); o.w = f2bf(v.w);
    ((ushort4*)dst)[i] = o;
}

// ---------------- GEMM: C[M,N] = A[M,K] * B[N,K]^T (+bias), XCD-swizzled 1D grid ----------------
// Tile = 128 x (NJ*32). NJ=4: 128x128 (gemm2). NJ=5: 128x160 (gemm1, 2560/160=16
// n-tiles -> 512 blocks = exactly 2/CU, no grid tail).
template<int BIAS, int OUTBF16, int NJ>
__global__ __launch_bounds__(256, 2)
void gemm_bt(const u16* __restrict__ A, const u16* __restrict__ B,
             const float* __restrict__ bias, void* __restrict__ Cout,
             int M, int N, int K, int mt, int nwg)
{
    __shared__ u16 ldsA[2][8192];            // A tile: [128 rows][64 k]
    __shared__ u16 ldsB[2][NJ * 2048];       // B tile: [NJ*32 rows][64 k]
    const int l = threadIdx.x & 63;
    const int w = threadIdx.x >> 6;
    const int bid = blockIdx.x;
    const int wg = (bid & 7) * (nwg >> 3) + (bid >> 3);
    const int m0 = (wg % mt) * 128, n0 = (wg / mt) * (NJ * 32);
    const int wm = (w >> 1) * 64, wn = (w & 1) * (NJ * 16);
    f32x4 acc[4][NJ] = {};

    const int lbyte = ((l & 7) * 16) ^ ((l >> 3) << 4);

    auto stage = [&](int buf, int k0) {
        #pragma unroll
        for (int inst = 0; inst < 4; ++inst) {
            int row = inst * 32 + w * 8 + (l >> 3);
            const u16* sa = A + (size_t)(m0 + row) * K + k0 + (lbyte >> 1);
            __builtin_amdgcn_global_load_lds(
                (const AS1 void*)sa,
                (AS3 void*)&ldsA[buf][inst * 2048 + w * 512], 16, 0, 0);
        }
        #pragma unroll
        for (int inst = 0; inst < NJ; ++inst) {
            int row = inst * 32 + w * 8 + (l >> 3);
            const u16* sb = B + (size_t)(n0 + row) * K + k0 + (lbyte >> 1);
            __builtin_amdgcn_global_load_lds(
                (const AS1 void*)sb,
                (AS3 void*)&ldsB[buf][inst * 2048 + w * 512], 16, 0, 0);
        }
    };

    auto compute = [&](int buf) {
        const char* Ab = (const char*)&ldsA[buf][0];
        const char* Bb = (const char*)&ldsB[buf][0];
        #pragma unroll
        for (int kk = 0; kk < 2; ++kk) {
            int ac2 = kk * 64 + (l >> 4) * 16;
            bf16x8 af[4], bfr[NJ];
            #pragma unroll
            for (int i = 0; i < 4; ++i) {
                int ar = wm + i * 16 + (l & 15);
                af[i] = *(const bf16x8*)(Ab + ar * 128 + (ac2 ^ ((ar & 7) << 4)));
            }
            #pragma unroll
            for (int j = 0; j < NJ; ++j) {
                int br = wn + j * 16 + (l & 15);
                bfr[j] = *(const bf16x8*)(Bb + br * 128 + (ac2 ^ ((br & 7) << 4)));
            }
            #pragma unroll
            for (int i = 0; i < 4; ++i)
                #pragma unroll
                for (int j = 0; j < NJ; ++j)
                    acc[i][j] = __builtin_amdgcn_mfma_f32_16x16x32_bf16(af[i], bfr[j], acc[i][j], 0, 0, 0);
        }
    };

    stage(0, 0);
    const int NT = K >> 6;
    for (int kt = 0; kt < NT; ++kt) {
        __syncthreads();
        if (kt + 1 < NT) stage((kt + 1) & 1, (kt + 1) << 6);
        compute(kt & 1);
    }

    #pragma unroll
    for (int j = 0; j < NJ; ++j) {
        int col = n0 + wn + j * 16 + (l & 15);
        float bv = BIAS ? bias[col] : 0.0f;
        #pragma unroll
        for (int i = 0; i < 4; ++i) {
            int row = m0 + wm + i * 16 + (l >> 4) * 4;
            #pragma unroll
            for (int r = 0; r < 4; ++r) {
                float v = acc[i][j][r] + bv;
                if (OUTBF16)
                    ((u16*)Cout)[(size_t)(row + r) * N + col] = f2bf(v);
                else
                    ((float*)Cout)[(size_t)(row + r) * N + col] = v;
            }
        }
    }
}

// ---------------- RoPE + scatter, cos/sin-deduplicated ----------------
__global__ __launch_bounds__(256)
void rope_scatter2(const u16* __restrict__ qkv,
                   const float* __restrict__ cosb,
                   const float* __restrict__ sinb,
                   u16* __restrict__ Q, u16* __restrict__ Kb, u16* __restrict__ Vt)
{
    int n = blockIdx.x * 256 + threadIdx.x;       // [0, NB*NS*128)
    const int d = n & 127;
    const int bs = n >> 7;                        // b*NS + s
    const int b = bs >> 11, s = bs & 2047;

    const float cs = cosb[(size_t)bs * NHD + d];
    const float sn = sinb[(size_t)bs * NHD + d];
    const int pd = (d < 64) ? d + 64 : d - 64;
    const float psign = (d < 64) ? -1.0f : 1.0f;

    const u16* row = qkv + (size_t)bs * NQKV;

    #pragma unroll
    for (int h = 0; h < NH; ++h) {
        float x = bf2f(row[h * NHD + d]);
        float p = bf2f(row[h * NHD + pd]);
        float v = (x * cs + psign * p * sn) * QSCALE;
        Q[(((size_t)b * NH + h) * NS + s) * NHD + d] = f2bf(v);
    }
    #pragma unroll
    for (int kh = 0; kh < NKH; ++kh) {
        float x = bf2f(row[NH * NHD + kh * NHD + d]);
        float p = bf2f(row[NH * NHD + kh * NHD + pd]);
        float v = x * cs + psign * p * sn;
        Kb[(((size_t)b * NKH + kh) * NS + s) * NHD + d] = f2bf(v);
    }
    #pragma unroll
    for (int vh = 0; vh < NKH; ++vh) {
        Vt[(((size_t)b * NKH + vh) * NHD + d) * NS + s] = row[(NH + NKH) * NHD + vh * NHD + d];
    }
}

// ---------------- causal GQA flash attention v12: head-parallel waves, balanced pairs ----------------
__global__ __launch_bounds__(256, 2)
void attn_fwd12(const u16* __restrict__ Q, const u16* __restrict__ Kb,
                const u16* __restrict__ Vt, u16* __restrict__ Out)
{
    __shared__ u16 kl[2][8192];   // K tile: [64 rows][128 d] bf16, 16 KB per buf
    __shared__ u16 vl[2][8192];   // V tile: [128 d][64 kv] bf16, 16 KB per buf

    const int l = threadIdx.x & 63;
    const int w = threadIdx.x >> 6;
    const int bid = blockIdx.x;
    const int gi = bid >> 3;
    const int g = (gi < 32) ? (63 - gi) : (gi - 32);   // sweep1: 63..32, sweep2: 0..31
    const int rem = bid & 7;                  // (b, kh, pair)
    const int b = rem & 1;
    const int kh = (rem >> 1) & 1;
    const int h = kh * 8 + ((rem >> 2) & 1) * 4 + w;   // this wave's q-head
    const int c = l & 31, hi = l >> 5;
    const int q0 = g * 32;                    // all 4 waves: same 32 q-rows
    const int qend = q0 + 31;

    const u16* Qp = Q + (((size_t)b * NH + h) * NS + q0) * NHD;
    const u16* Kp = Kb + ((size_t)b * NKH + kh) * NS * NHD;
    const u16* Vp = Vt + ((size_t)b * NKH + kh) * (size_t)NHD * NS;

    bf16x8 qf[8];
    #pragma unroll
    for (int ds = 0; ds < 8; ++ds)
        qf[ds] = *(const bf16x8*)(Qp + c * NHD + ds * 16 + hi * 8);

    f32x16 o0 = {}, o1 = {}, o2 = {}, o3 = {};
    float m_run = -1e30f, l_run = 0.f;

    auto stage = [&](int buf, int kt) {
        const int kb = kt << 6;
        #pragma unroll
        for (int ii = 0; ii < 4; ++ii) {           // K: rows r, swizzled col chunks
            int r = w * 16 + ii * 4 + (l >> 4);
            int q = (l & 15) ^ ((ii * 4 + (l >> 4)) & 7);
            const u16* src = Kp + (size_t)(kb + r) * NHD + q * 8;
            __builtin_amdgcn_global_load_lds(
                (const AS1 void*)src,
                (AS3 void*)&kl[buf][(w * 4 + ii) * 512], 16, 0, 0);
        }
        #pragma unroll
        for (int ii = 0; ii < 4; ++ii) {           // V: rows d, swizzled kv chunks
            int jj = w * 4 + ii;
            int d = jj * 8 + (l >> 3);
            int q = (l & 7) ^ ((l >> 3) & 7);
            const u16* src = Vp + (size_t)d * NS + kb + q * 8;
            __builtin_amdgcn_global_load_lds(
                (const AS1 void*)src,
                (AS3 void*)&vl[buf][jj * 512], 16, 0, 0);
        }
    };

    const int NT = (g >> 1) + 1;               // exact causal range, 64-kv tiles
    stage(0, 0);
    __syncthreads();

    for (int kt = 0; kt < NT; ++kt) {
        const int kb = kt << 6;
        const int cur = kt & 1;
        if (kt + 1 < NT) stage(cur ^ 1, kt + 1);

        const bool do1 = (kb + 32 <= qend);
        {
            const bool diag0 = (kb == q0);
            const bool diag1 = (kb + 32 == q0);
            const char* Klb = (const char*)kl[cur];
            const char* Vlb = (const char*)vl[cur];

            f32x16 s0 = {}, s1 = {};
            __builtin_amdgcn_s_setprio(1);
            #pragma unroll
            for (int ds = 0; ds < 8; ++ds) {
                bf16x8 kf0 = *(const bf16x8*)(Klb + c * 256 + ((ds * 32 + hi * 16) ^ ((c & 7) << 4)));
                s0 = __builtin_amdgcn_mfma_f32_32x32x16_bf16(kf0, qf[ds], s0, 0, 0, 0);
            }
            if (do1) {
                #pragma unroll
                for (int ds = 0; ds < 8; ++ds) {
                    bf16x8 kf1 = *(const bf16x8*)(Klb + (32 + c) * 256 + ((ds * 32 + hi * 16) ^ ((c & 7) << 4)));
                    s1 = __builtin_amdgcn_mfma_f32_32x32x16_bf16(kf1, qf[ds], s1, 0, 0, 0);
                }
            }
            __builtin_amdgcn_s_setprio(0);

            float sv0[16], sv1[16];
            #pragma unroll
            for (int r = 0; r < 16; ++r) { sv0[r] = s0[r]; sv1[r] = do1 ? s1[r] : -1e30f; }

            if (diag0 || diag1) {
                #pragma unroll
                for (int r = 0; r < 16; ++r) {
                    int rr = (r & 3) + 8 * (r >> 2) + 4 * hi;
                    if (diag0) { if (rr > c) sv0[r] = -1e30f; }
                    else       { if (rr > c) sv1[r] = -1e30f; }
                }
            }

            float mx = -1e30f;
            #pragma unroll
            for (int r = 0; r < 16; ++r) mx = fmaxf(mx, fmaxf(sv0[r], sv1[r]));
            mx = redmax32(mx);

            if (__any(mx > m_run + 8.0f)) {
                float mnew = fmaxf(m_run, mx);
                float alpha = exp2f(m_run - mnew);
                m_run = mnew;
                l_run *= alpha;
                #pragma unroll
                for (int r = 0; r < 16; ++r) {
                    int qr = (r & 3) + 8 * (r >> 2) + 4 * hi;
                    float aR = __shfl(alpha, qr + (l & 32));
                    o0[r] *= aR; o1[r] *= aR; o2[r] *= aR; o3[r] *= aR;
                }
            }

            float e0[16], e1[16];
            float ls = 0.f;
            #pragma unroll
            for (int r = 0; r < 16; ++r) {
                e0[r] = exp2f(sv0[r] - m_run);
                e1[r] = exp2f(sv1[r] - m_run);
                ls += e0[r] + e1[r];
            }
            l_run += redsum32(ls);

            bf16x8 pa[4];
            #pragma unroll
            for (int ks = 0; ks < 4; ++ks) {
                const float* pe = (ks < 2) ? e0 : e1;
                const int b8 = (ks & 1) * 8;
                unsigned A  = pk2(pe[b8 + 0], pe[b8 + 1]);
                unsigned Bq = pk2(pe[b8 + 4], pe[b8 + 5]);
                unsigned C2 = pk2(pe[b8 + 2], pe[b8 + 3]);
                unsigned D2 = pk2(pe[b8 + 6], pe[b8 + 7]);
                pl32swap(A, Bq);
                pl32swap(C2, D2);
                union { uint4 u; bf16x8 v; } cv;
                cv.u.x = A;
                cv.u.y = C2;
                cv.u.z = Bq;
                cv.u.w = D2;
                pa[ks] = cv.v;
            }

            __builtin_amdgcn_s_setprio(1);
            #pragma unroll
            for (int ks = 0; ks < 4; ++ks) {
                if (ks >= 2 && !do1) continue;
                const int ko = (ks * 32 + hi * 16);
                bf16x8 vf;
                vf = *(const bf16x8*)(Vlb + (0 * 32 + c) * 128 + (ko ^ ((c & 7) << 4)));
                o0 = __builtin_amdgcn_mfma_f32_32x32x16_bf16(pa[ks], vf, o0, 0, 0, 0);
                vf = *(const bf16x8*)(Vlb + (1 * 32 + c) * 128 + (ko ^ ((c & 7) << 4)));
                o1 = __builtin_amdgcn_mfma_f32_32x32x16_bf16(pa[ks], vf, o1, 0, 0, 0);
                vf = *(const bf16x8*)(Vlb + (2 * 32 + c) * 128 + (ko ^ ((c & 7) << 4)));
                o2 = __builtin_amdgcn_mfma_f32_32x32x16_bf16(pa[ks], vf, o2, 0, 0, 0);
                vf = *(const bf16x8*)(Vlb + (3 * 32 + c) * 128 + (ko ^ ((c & 7) << 4)));
                o3 = __builtin_amdgcn_mfma_f32_32x32x16_bf16(pa[ks], vf, o3, 0, 0, 0);
            }
            __builtin_amdgcn_s_setprio(0);
        }
        __syncthreads();
    }

    const float linv = 1.0f / l_run;
    #pragma unroll
    for (int r = 0; r < 16; ++r) {
        int qr = (r & 3) + 8 * (r >> 2) + 4 * hi;
        float lr = __shfl(linv, qr + (l & 32));
        size_t base = ((size_t)(b * NS + q0 + qr)) * (NH * NHD) + h * NHD;
        Out[base + c]      = f2bf(o0[r] * lr);
        Out[base + 32 + c] = f2bf(o1[r] * lr);
        Out[base + 64 + c] = f2bf(o2[r] * lr);
        Out[base + 96 + c] = f2bf(o3[r] * lr);
    }
}

// ---------------- host launcher ----------------
extern "C" void kernel_launch(void* const* d_in, const int* in_sizes, int n_in,
                              void* d_out, int out_size, void* d_ws, size_t ws_size,
                              hipStream_t stream)
{
    (void)in_sizes; (void)n_in; (void)out_size; (void)ws_size;
    const float* hidden = (const float*)d_in[0];
    const float* cosb   = (const float*)d_in[1];
    const float* sinb   = (const float*)d_in[2];
    const float* qkv_w  = (const float*)d_in[3];
    const float* qkv_b  = (const float*)d_in[4];
    const float* o_w    = (const float*)d_in[5];
    float* out = (float*)d_out;

    char* ws = (char*)d_ws;
    size_t off = 0;
    auto alloc = [&](size_t bytes) {
        void* p = ws + off; off += (bytes + 255) & ~(size_t)255; return p;
    };
    u16* hid_bf  = (u16*)alloc((size_t)NB * NS * ND * 2);
    u16* qkvw_bf = (u16*)alloc((size_t)NQKV * ND * 2);
    u16* ow_bf   = (u16*)alloc((size_t)ND * NH * NHD * 2);
    u16* qkv     = (u16*)alloc((size_t)NB * NS * NQKV * 2);
    u16* Qb      = (u16*)alloc((size_t)NB * NH * NS * NHD * 2);
    u16* Kb      = (u16*)alloc((size_t)NB * NKH * NS * NHD * 2);
    u16* Vt      = (u16*)alloc((size_t)NB * NKH * NS * NHD * 2);
    u16* attn    = hid_bf;   // alias: hidden_bf16 dead after GEMM1

    int n1 = NB * NS * ND / 4;
    int n2 = NQKV * ND / 4;
    int n3 = ND * NH * NHD / 4;
    cvt_all<<<(n1 + n2 + n3 + 255) / 256, 256, 0, stream>>>(
        hidden, hid_bf, n1, qkv_w, qkvw_bf, n2, o_w, ow_bf, n3);

    // GEMM1: 128x160 tiles -> 32 x 16 = 512 blocks, exactly 2/CU (no tail)
    int nwg1 = (NB * NS / 128) * (NQKV / 160);     // 512
    gemm_bt<1, 1, 5><<<nwg1, 256, 0, stream>>>(hid_bf, qkvw_bf, qkv_b, qkv,
                                               NB * NS, NQKV, ND, NB * NS / 128, nwg1);

    int nr = NB * NS * NHD;                        // one thread per (bs, d)
    rope_scatter2<<<nr / 256, 256, 0, stream>>>(qkv, cosb, sinb, Qb, Kb, Vt);

    attn_fwd12<<<512, 256, 0, stream>>>(Qb, Kb, Vt, attn);

    int nwg2 = (NB * NS / 128) * (ND / 128);       // 512
    gemm_bt<0, 0, 4><<<nwg2, 256, 0, stream>>>(attn, ow_bf, nullptr, out,
                                               NB * NS, ND, NH * NHD, NB * NS / 128, nwg2);
}

// Round 20
// 201.748 us; speedup vs baseline: 1.0944x; 1.0054x over previous
//
#include <hip/hip_runtime.h>

typedef unsigned short u16;
typedef __attribute__((ext_vector_type(8))) __bf16 bf16x8;
typedef __attribute__((ext_vector_type(2))) __bf16 bf16x2;
typedef __attribute__((ext_vector_type(4))) float f32x4;
typedef __attribute__((ext_vector_type(16))) float f32x16;
typedef __attribute__((ext_vector_type(2))) unsigned u32x2;

#define NB 2
#define NS 2048
#define ND 2048
#define NH 16
#define NKH 2
#define NHD 128
#define NQKV 2560
// 1/sqrt(128) * log2(e): scores in log2 domain -> exp2f = raw v_exp_f32
#define QSCALE (0.08838834764831845f * 1.4426950408889634f)

#define AS1 __attribute__((address_space(1)))
#define AS3 __attribute__((address_space(3)))

__device__ __forceinline__ u16 f2bf(float x) {
    union { float f; unsigned u; } v; v.f = x;
    unsigned r = v.u + 0x7fffu + ((v.u >> 16) & 1u);
    return (u16)(r >> 16);
}
__device__ __forceinline__ float bf2f(u16 x) {
    union { unsigned u; float f; } v; v.u = ((unsigned)x) << 16;
    return v.f;
}
__device__ __forceinline__ unsigned pk2(float lo, float hi_) {
    union { bf16x2 v; unsigned u; } t;
    t.v.x = (__bf16)lo; t.v.y = (__bf16)hi_;
    return t.u;
}
__device__ __forceinline__ void pl32swap(unsigned &a, unsigned &b) {
#if __has_builtin(__builtin_amdgcn_permlane32_swap)
    u32x2 r = __builtin_amdgcn_permlane32_swap(a, b, false, false);
    a = r.x; b = r.y;
#else
    asm volatile("v_permlane32_swap_b32 %0, %1" : "+v"(a), "+v"(b));
#endif
}
__device__ __forceinline__ float fbits(unsigned u) {
    union { unsigned u; float f; } v; v.u = u; return v.f;
}
__device__ __forceinline__ unsigned ubits(float f) {
    union { float f; unsigned u; } v; v.f = f; return v.u;
}
__device__ __forceinline__ float redmax32(float x) {
    unsigned a = ubits(x), b = a;
    pl32swap(a, b);
    return fmaxf(fbits(a), fbits(b));
}
__device__ __forceinline__ float redsum32(float x) {
    unsigned a = ubits(x), b = a;
    pl32swap(a, b);
    return fbits(a) + fbits(b);
}

// ---------------- fp32 -> bf16 conversion: all three inputs, one launch ----------------
__global__ void cvt_all(const float* __restrict__ a, u16* __restrict__ oa, int na,
                        const float* __restrict__ b, u16* __restrict__ ob, int nb,
                        const float* __restrict__ c, u16* __restrict__ oc, int nc)
{
    int i = blockIdx.x * 256 + threadIdx.x;
    const float* src; u16* dst;
    if (i < na)            { src = a; dst = oa; }
    else if (i < na + nb)  { src = b; dst = ob; i -= na; }
    else if (i < na + nb + nc) { src = c; dst = oc; i -= na + nb; }
    else return;
    float4 v = ((const float4*)src)[i];
    ushort4 o;
    o.x = f2bf(v.x); o.y = f2bf(v.y); o.z = f2bf(v.z); o.w = f2bf(v.w);
    ((ushort4*)dst)[i] = o;
}

// ---------------- GEMM: C[M,N] = A[M,K] * B[N,K]^T (+bias), XCD-swizzled 1D grid ----------------
// Tile = 128 x (NJ*32). NJ=4: 128x128 (gemm2). NJ=5: 128x160 (gemm1, 512 blocks = 2/CU).
template<int BIAS, int OUTBF16, int NJ>
__global__ __launch_bounds__(256, 2)
void gemm_bt(const u16* __restrict__ A, const u16* __restrict__ B,
             const float* __restrict__ bias, void* __restrict__ Cout,
             int M, int N, int K, int mt, int nwg)
{
    __shared__ u16 ldsA[2][8192];            // A tile: [128 rows][64 k]
    __shared__ u16 ldsB[2][NJ * 2048];       // B tile: [NJ*32 rows][64 k]
    const int l = threadIdx.x & 63;
    const int w = threadIdx.x >> 6;
    const int bid = blockIdx.x;
    const int wg = (bid & 7) * (nwg >> 3) + (bid >> 3);
    const int m0 = (wg % mt) * 128, n0 = (wg / mt) * (NJ * 32);
    const int wm = (w >> 1) * 64, wn = (w & 1) * (NJ * 16);
    f32x4 acc[4][NJ] = {};

    const int lbyte = ((l & 7) * 16) ^ ((l >> 3) << 4);

    auto stage = [&](int buf, int k0) {
        #pragma unroll
        for (int inst = 0; inst < 4; ++inst) {
            int row = inst * 32 + w * 8 + (l >> 3);
            const u16* sa = A + (size_t)(m0 + row) * K + k0 + (lbyte >> 1);
            __builtin_amdgcn_global_load_lds(
                (const AS1 void*)sa,
                (AS3 void*)&ldsA[buf][inst * 2048 + w * 512], 16, 0, 0);
        }
        #pragma unroll
        for (int inst = 0; inst < NJ; ++inst) {
            int row = inst * 32 + w * 8 + (l >> 3);
            const u16* sb = B + (size_t)(n0 + row) * K + k0 + (lbyte >> 1);
            __builtin_amdgcn_global_load_lds(
                (const AS1 void*)sb,
                (AS3 void*)&ldsB[buf][inst * 2048 + w * 512], 16, 0, 0);
        }
    };

    auto compute = [&](int buf) {
        const char* Ab = (const char*)&ldsA[buf][0];
        const char* Bb = (const char*)&ldsB[buf][0];
        #pragma unroll
        for (int kk = 0; kk < 2; ++kk) {
            int ac2 = kk * 64 + (l >> 4) * 16;
            bf16x8 af[4], bfr[NJ];
            #pragma unroll
            for (int i = 0; i < 4; ++i) {
                int ar = wm + i * 16 + (l & 15);
                af[i] = *(const bf16x8*)(Ab + ar * 128 + (ac2 ^ ((ar & 7) << 4)));
            }
            #pragma unroll
            for (int j = 0; j < NJ; ++j) {
                int br = wn + j * 16 + (l & 15);
                bfr[j] = *(const bf16x8*)(Bb + br * 128 + (ac2 ^ ((br & 7) << 4)));
            }
            #pragma unroll
            for (int i = 0; i < 4; ++i)
                #pragma unroll
                for (int j = 0; j < NJ; ++j)
                    acc[i][j] = __builtin_amdgcn_mfma_f32_16x16x32_bf16(af[i], bfr[j], acc[i][j], 0, 0, 0);
        }
    };

    stage(0, 0);
    const int NT = K >> 6;
    for (int kt = 0; kt < NT; ++kt) {
        __syncthreads();
        if (kt + 1 < NT) stage((kt + 1) & 1, (kt + 1) << 6);
        compute(kt & 1);
    }

    #pragma unroll
    for (int j = 0; j < NJ; ++j) {
        int col = n0 + wn + j * 16 + (l & 15);
        float bv = BIAS ? bias[col] : 0.0f;
        #pragma unroll
        for (int i = 0; i < 4; ++i) {
            int row = m0 + wm + i * 16 + (l >> 4) * 4;
            #pragma unroll
            for (int r = 0; r < 4; ++r) {
                float v = acc[i][j][r] + bv;
                if (OUTBF16)
                    ((u16*)Cout)[(size_t)(row + r) * N + col] = f2bf(v);
                else
                    ((float*)Cout)[(size_t)(row + r) * N + col] = v;
            }
        }
    }
}

// ---------------- RoPE + scatter, cos/sin-deduplicated ----------------
__global__ __launch_bounds__(256)
void rope_scatter2(const u16* __restrict__ qkv,
                   const float* __restrict__ cosb,
                   const float* __restrict__ sinb,
                   u16* __restrict__ Q, u16* __restrict__ Kb, u16* __restrict__ Vt)
{
    int n = blockIdx.x * 256 + threadIdx.x;       // [0, NB*NS*128)
    const int d = n & 127;
    const int bs = n >> 7;                        // b*NS + s
    const int b = bs >> 11, s = bs & 2047;

    const float cs = cosb[(size_t)bs * NHD + d];
    const float sn = sinb[(size_t)bs * NHD + d];
    const int pd = (d < 64) ? d + 64 : d - 64;
    const float psign = (d < 64) ? -1.0f : 1.0f;

    const u16* row = qkv + (size_t)bs * NQKV;

    #pragma unroll
    for (int h = 0; h < NH; ++h) {
        float x = bf2f(row[h * NHD + d]);
        float p = bf2f(row[h * NHD + pd]);
        float v = (x * cs + psign * p * sn) * QSCALE;
        Q[(((size_t)b * NH + h) * NS + s) * NHD + d] = f2bf(v);
    }
    #pragma unroll
    for (int kh = 0; kh < NKH; ++kh) {
        float x = bf2f(row[NH * NHD + kh * NHD + d]);
        float p = bf2f(row[NH * NHD + kh * NHD + pd]);
        float v = x * cs + psign * p * sn;
        Kb[(((size_t)b * NKH + kh) * NS + s) * NHD + d] = f2bf(v);
    }
    #pragma unroll
    for (int vh = 0; vh < NKH; ++vh) {
        Vt[(((size_t)b * NKH + vh) * NHD + d) * NS + s] = row[(NH + NKH) * NHD + vh * NHD + d];
    }
}

// ---------------- causal GQA flash attention v13: single-buffered V, 48KB LDS ----------------
// v12 mapping (head-parallel waves, balanced g pairs) with V single-buffered:
// LDS 64->48 KB -> 3 blocks/CU = 12 waves/CU (+50% TLP). V(t+1) staged after
// the post-PV barrier (all readers done), drained by next iter's pre-PV
// barrier; its latency hides under QK^T+softmax. All access patterns and
// math byte-identical to v12.
__global__ __launch_bounds__(256, 2)
void attn_fwd13(const u16* __restrict__ Q, const u16* __restrict__ Kb,
                const u16* __restrict__ Vt, u16* __restrict__ Out)
{
    __shared__ u16 kl[2][8192];   // K tile: [64 rows][128 d] bf16, double-buffered
    __shared__ u16 vl[8192];      // V tile: [128 d][64 kv] bf16, single-buffered

    const int l = threadIdx.x & 63;
    const int w = threadIdx.x >> 6;
    const int bid = blockIdx.x;
    const int gi = bid >> 3;
    const int g = (gi < 32) ? (63 - gi) : (gi - 32);   // sweep1: 63..32, sweep2: 0..31
    const int rem = bid & 7;                  // (b, kh, pair)
    const int b = rem & 1;
    const int kh = (rem >> 1) & 1;
    const int h = kh * 8 + ((rem >> 2) & 1) * 4 + w;   // this wave's q-head
    const int c = l & 31, hi = l >> 5;
    const int q0 = g * 32;                    // all 4 waves: same 32 q-rows
    const int qend = q0 + 31;

    const u16* Qp = Q + (((size_t)b * NH + h) * NS + q0) * NHD;
    const u16* Kp = Kb + ((size_t)b * NKH + kh) * NS * NHD;
    const u16* Vp = Vt + ((size_t)b * NKH + kh) * (size_t)NHD * NS;

    bf16x8 qf[8];
    #pragma unroll
    for (int ds = 0; ds < 8; ++ds)
        qf[ds] = *(const bf16x8*)(Qp + c * NHD + ds * 16 + hi * 8);

    f32x16 o0 = {}, o1 = {}, o2 = {}, o3 = {};
    float m_run = -1e30f, l_run = 0.f;

    auto stageK = [&](int buf, int kt) {
        const int kb = kt << 6;
        #pragma unroll
        for (int ii = 0; ii < 4; ++ii) {           // K: rows r, swizzled col chunks
            int r = w * 16 + ii * 4 + (l >> 4);
            int q = (l & 15) ^ ((ii * 4 + (l >> 4)) & 7);
            const u16* src = Kp + (size_t)(kb + r) * NHD + q * 8;
            __builtin_amdgcn_global_load_lds(
                (const AS1 void*)src,
                (AS3 void*)&kl[buf][(w * 4 + ii) * 512], 16, 0, 0);
        }
    };
    auto stageV = [&](int kt) {
        const int kb = kt << 6;
        #pragma unroll
        for (int ii = 0; ii < 4; ++ii) {           // V: rows d, swizzled kv chunks
            int jj = w * 4 + ii;
            int d = jj * 8 + (l >> 3);
            int q = (l & 7) ^ ((l >> 3) & 7);
            const u16* src = Vp + (size_t)d * NS + kb + q * 8;
            __builtin_amdgcn_global_load_lds(
                (const AS1 void*)src,
                (AS3 void*)&vl[jj * 512], 16, 0, 0);
        }
    };

    const int NT = (g >> 1) + 1;               // exact causal range, 64-kv tiles
    stageK(0, 0);
    stageV(0);
    __syncthreads();                           // K(0), V(0) resident

    for (int kt = 0; kt < NT; ++kt) {
        const int kb = kt << 6;
        const int cur = kt & 1;
        if (kt + 1 < NT) stageK(cur ^ 1, kt + 1);

        const bool do1 = (kb + 32 <= qend);
        const bool diag0 = (kb == q0);
        const bool diag1 = (kb + 32 == q0);
        const char* Klb = (const char*)kl[cur];
        const char* Vlb = (const char*)vl;

        f32x16 s0 = {}, s1 = {};
        __builtin_amdgcn_s_setprio(1);
        #pragma unroll
        for (int ds = 0; ds < 8; ++ds) {
            bf16x8 kf0 = *(const bf16x8*)(Klb + c * 256 + ((ds * 32 + hi * 16) ^ ((c & 7) << 4)));
            s0 = __builtin_amdgcn_mfma_f32_32x32x16_bf16(kf0, qf[ds], s0, 0, 0, 0);
        }
        if (do1) {
            #pragma unroll
            for (int ds = 0; ds < 8; ++ds) {
                bf16x8 kf1 = *(const bf16x8*)(Klb + (32 + c) * 256 + ((ds * 32 + hi * 16) ^ ((c & 7) << 4)));
                s1 = __builtin_amdgcn_mfma_f32_32x32x16_bf16(kf1, qf[ds], s1, 0, 0, 0);
            }
        }
        __builtin_amdgcn_s_setprio(0);

        float sv0[16], sv1[16];
        #pragma unroll
        for (int r = 0; r < 16; ++r) { sv0[r] = s0[r]; sv1[r] = do1 ? s1[r] : -1e30f; }

        if (diag0 || diag1) {
            #pragma unroll
            for (int r = 0; r < 16; ++r) {
                int rr = (r & 3) + 8 * (r >> 2) + 4 * hi;
                if (diag0) { if (rr > c) sv0[r] = -1e30f; }
                else       { if (rr > c) sv1[r] = -1e30f; }
            }
        }

        float mx = -1e30f;
        #pragma unroll
        for (int r = 0; r < 16; ++r) mx = fmaxf(mx, fmaxf(sv0[r], sv1[r]));
        mx = redmax32(mx);

        if (__any(mx > m_run + 8.0f)) {
            float mnew = fmaxf(m_run, mx);
            float alpha = exp2f(m_run - mnew);
            m_run = mnew;
            l_run *= alpha;
            #pragma unroll
            for (int r = 0; r < 16; ++r) {
                int qr = (r & 3) + 8 * (r >> 2) + 4 * hi;
                float aR = __shfl(alpha, qr + (l & 32));
                o0[r] *= aR; o1[r] *= aR; o2[r] *= aR; o3[r] *= aR;
            }
        }

        float e0[16], e1[16];
        float ls = 0.f;
        #pragma unroll
        for (int r = 0; r < 16; ++r) {
            e0[r] = exp2f(sv0[r] - m_run);
            e1[r] = exp2f(sv1[r] - m_run);
            ls += e0[r] + e1[r];
        }
        l_run += redsum32(ls);

        bf16x8 pa[4];
        #pragma unroll
        for (int ks = 0; ks < 4; ++ks) {
            const float* pe = (ks < 2) ? e0 : e1;
            const int b8 = (ks & 1) * 8;
            unsigned A  = pk2(pe[b8 + 0], pe[b8 + 1]);
            unsigned Bq = pk2(pe[b8 + 4], pe[b8 + 5]);
            unsigned C2 = pk2(pe[b8 + 2], pe[b8 + 3]);
            unsigned D2 = pk2(pe[b8 + 6], pe[b8 + 7]);
            pl32swap(A, Bq);
            pl32swap(C2, D2);
            union { uint4 u; bf16x8 v; } cv;
            cv.u.x = A;
            cv.u.y = C2;
            cv.u.z = Bq;
            cv.u.w = D2;
            pa[ks] = cv.v;
        }

        __syncthreads();          // drain vmcnt: V(kt) resident (and K(kt+1));
                                  // all waves past QK reads of kl[cur]

        __builtin_amdgcn_s_setprio(1);
        #pragma unroll
        for (int ks = 0; ks < 4; ++ks) {
            if (ks >= 2 && !do1) continue;
            const int ko = (ks * 32 + hi * 16);
            bf16x8 vf;
            vf = *(const bf16x8*)(Vlb + (0 * 32 + c) * 128 + (ko ^ ((c & 7) << 4)));
            o0 = __builtin_amdgcn_mfma_f32_32x32x16_bf16(pa[ks], vf, o0, 0, 0, 0);
            vf = *(const bf16x8*)(Vlb + (1 * 32 + c) * 128 + (ko ^ ((c & 7) << 4)));
            o1 = __builtin_amdgcn_mfma_f32_32x32x16_bf16(pa[ks], vf, o1, 0, 0, 0);
            vf = *(const bf16x8*)(Vlb + (2 * 32 + c) * 128 + (ko ^ ((c & 7) << 4)));
            o2 = __builtin_amdgcn_mfma_f32_32x32x16_bf16(pa[ks], vf, o2, 0, 0, 0);
            vf = *(const bf16x8*)(Vlb + (3 * 32 + c) * 128 + (ko ^ ((c & 7) << 4)));
            o3 = __builtin_amdgcn_mfma_f32_32x32x16_bf16(pa[ks], vf, o3, 0, 0, 0);
        }
        __builtin_amdgcn_s_setprio(0);

        __syncthreads();          // all waves done reading vl
        if (kt + 1 < NT) stageV(kt + 1);   // overwrite vl; lands during next QK
    }

    const float linv = 1.0f / l_run;
    #pragma unroll
    for (int r = 0; r < 16; ++r) {
        int qr = (r & 3) + 8 * (r >> 2) + 4 * hi;
        float lr = __shfl(linv, qr + (l & 32));
        size_t base = ((size_t)(b * NS + q0 + qr)) * (NH * NHD) + h * NHD;
        Out[base + c]      = f2bf(o0[r] * lr);
        Out[base + 32 + c] = f2bf(o1[r] * lr);
        Out[base + 64 + c] = f2bf(o2[r] * lr);
        Out[base + 96 + c] = f2bf(o3[r] * lr);
    }
}

// ---------------- host launcher ----------------
extern "C" void kernel_launch(void* const* d_in, const int* in_sizes, int n_in,
                              void* d_out, int out_size, void* d_ws, size_t ws_size,
                              hipStream_t stream)
{
    (void)in_sizes; (void)n_in; (void)out_size; (void)ws_size;
    const float* hidden = (const float*)d_in[0];
    const float* cosb   = (const float*)d_in[1];
    const float* sinb   = (const float*)d_in[2];
    const float* qkv_w  = (const float*)d_in[3];
    const float* qkv_b  = (const float*)d_in[4];
    const float* o_w    = (const float*)d_in[5];
    float* out = (float*)d_out;

    char* ws = (char*)d_ws;
    size_t off = 0;
    auto alloc = [&](size_t bytes) {
        void* p = ws + off; off += (bytes + 255) & ~(size_t)255; return p;
    };
    u16* hid_bf  = (u16*)alloc((size_t)NB * NS * ND * 2);
    u16* qkvw_bf = (u16*)alloc((size_t)NQKV * ND * 2);
    u16* ow_bf   = (u16*)alloc((size_t)ND * NH * NHD * 2);
    u16* qkv     = (u16*)alloc((size_t)NB * NS * NQKV * 2);
    u16* Qb      = (u16*)alloc((size_t)NB * NH * NS * NHD * 2);
    u16* Kb      = (u16*)alloc((size_t)NB * NKH * NS * NHD * 2);
    u16* Vt      = (u16*)alloc((size_t)NB * NKH * NS * NHD * 2);
    u16* attn    = hid_bf;   // alias: hidden_bf16 dead after GEMM1

    int n1 = NB * NS * ND / 4;
    int n2 = NQKV * ND / 4;
    int n3 = ND * NH * NHD / 4;
    cvt_all<<<(n1 + n2 + n3 + 255) / 256, 256, 0, stream>>>(
        hidden, hid_bf, n1, qkv_w, qkvw_bf, n2, o_w, ow_bf, n3);

    // GEMM1: 128x160 tiles -> 32 x 16 = 512 blocks, exactly 2/CU (no tail)
    int nwg1 = (NB * NS / 128) * (NQKV / 160);     // 512
    gemm_bt<1, 1, 5><<<nwg1, 256, 0, stream>>>(hid_bf, qkvw_bf, qkv_b, qkv,
                                               NB * NS, NQKV, ND, NB * NS / 128, nwg1);

    int nr = NB * NS * NHD;                        // one thread per (bs, d)
    rope_scatter2<<<nr / 256, 256, 0, stream>>>(qkv, cosb, sinb, Qb, Kb, Vt);

    attn_fwd13<<<512, 256, 0, stream>>>(Qb, Kb, Vt, attn);

    int nwg2 = (NB * NS / 128) * (ND / 128);       // 512
    gemm_bt<0, 0, 4><<<nwg2, 256, 0, stream>>>(attn, ow_bf, nullptr, out,
                                               NB * NS, ND, NH * NHD, NB * NS / 128, nwg2);
}

// Round 21
// 201.689 us; speedup vs baseline: 1.0947x; 1.0003x over previous
//
#include <hip/hip_runtime.h>

typedef unsigned short u16;
typedef __attribute__((ext_vector_type(8))) __bf16 bf16x8;
typedef __attribute__((ext_vector_type(2))) __bf16 bf16x2;
typedef __attribute__((ext_vector_type(4))) float f32x4;
typedef __attribute__((ext_vector_type(16))) float f32x16;
typedef __attribute__((ext_vector_type(2))) unsigned u32x2;

#define NB 2
#define NS 2048
#define ND 2048
#define NH 16
#define NKH 2
#define NHD 128
#define NQKV 2560
// 1/sqrt(128) * log2(e): scores in log2 domain -> exp2f = raw v_exp_f32
#define QSCALE (0.08838834764831845f * 1.4426950408889634f)

#define AS1 __attribute__((address_space(1)))
#define AS3 __attribute__((address_space(3)))

__device__ __forceinline__ u16 f2bf(float x) {
    union { float f; unsigned u; } v; v.f = x;
    unsigned r = v.u + 0x7fffu + ((v.u >> 16) & 1u);
    return (u16)(r >> 16);
}
__device__ __forceinline__ float bf2f(u16 x) {
    union { unsigned u; float f; } v; v.u = ((unsigned)x) << 16;
    return v.f;
}
__device__ __forceinline__ unsigned pk2(float lo, float hi_) {
    union { bf16x2 v; unsigned u; } t;
    t.v.x = (__bf16)lo; t.v.y = (__bf16)hi_;
    return t.u;
}
__device__ __forceinline__ void pl32swap(unsigned &a, unsigned &b) {
#if __has_builtin(__builtin_amdgcn_permlane32_swap)
    u32x2 r = __builtin_amdgcn_permlane32_swap(a, b, false, false);
    a = r.x; b = r.y;
#else
    asm volatile("v_permlane32_swap_b32 %0, %1" : "+v"(a), "+v"(b));
#endif
}
__device__ __forceinline__ float fbits(unsigned u) {
    union { unsigned u; float f; } v; v.u = u; return v.f;
}
__device__ __forceinline__ unsigned ubits(float f) {
    union { float f; unsigned u; } v; v.f = f; return v.u;
}
__device__ __forceinline__ float redmax32(float x) {
    unsigned a = ubits(x), b = a;
    pl32swap(a, b);
    return fmaxf(fbits(a), fbits(b));
}
__device__ __forceinline__ float redsum32(float x) {
    unsigned a = ubits(x), b = a;
    pl32swap(a, b);
    return fbits(a) + fbits(b);
}

// ---------------- fp32 -> bf16 conversion: all three inputs, one launch ----------------
__global__ void cvt_all(const float* __restrict__ a, u16* __restrict__ oa, int na,
                        const float* __restrict__ b, u16* __restrict__ ob, int nb,
                        const float* __restrict__ c, u16* __restrict__ oc, int nc)
{
    int i = blockIdx.x * 256 + threadIdx.x;
    const float* src; u16* dst;
    if (i < na)            { src = a; dst = oa; }
    else if (i < na + nb)  { src = b; dst = ob; i -= na; }
    else if (i < na + nb + nc) { src = c; dst = oc; i -= na + nb; }
    else return;
    float4 v = ((const float4*)src)[i];
    ushort4 o;
    o.x = f2bf(v.x); o.y = f2bf(v.y); o.z = f2bf(v.z); o.w = f2bf(v.w);
    ((ushort4*)dst)[i] = o;
}

// ---------------- GEMM: C[M,N] = A[M,K] * B[N,K]^T (+bias), XCD-swizzled 1D grid ----------------
// Tile = 128 x (NJ*32). NJ=4: 128x128 (gemm2). NJ=5: 128x160 (gemm1, 512 blocks = 2/CU).
template<int BIAS, int OUTBF16, int NJ>
__global__ __launch_bounds__(256, 2)
void gemm_bt(const u16* __restrict__ A, const u16* __restrict__ B,
             const float* __restrict__ bias, void* __restrict__ Cout,
             int M, int N, int K, int mt, int nwg)
{
    __shared__ u16 ldsA[2][8192];            // A tile: [128 rows][64 k]
    __shared__ u16 ldsB[2][NJ * 2048];       // B tile: [NJ*32 rows][64 k]
    const int l = threadIdx.x & 63;
    const int w = threadIdx.x >> 6;
    const int bid = blockIdx.x;
    const int wg = (bid & 7) * (nwg >> 3) + (bid >> 3);
    const int m0 = (wg % mt) * 128, n0 = (wg / mt) * (NJ * 32);
    const int wm = (w >> 1) * 64, wn = (w & 1) * (NJ * 16);
    f32x4 acc[4][NJ] = {};

    const int lbyte = ((l & 7) * 16) ^ ((l >> 3) << 4);

    auto stage = [&](int buf, int k0) {
        #pragma unroll
        for (int inst = 0; inst < 4; ++inst) {
            int row = inst * 32 + w * 8 + (l >> 3);
            const u16* sa = A + (size_t)(m0 + row) * K + k0 + (lbyte >> 1);
            __builtin_amdgcn_global_load_lds(
                (const AS1 void*)sa,
                (AS3 void*)&ldsA[buf][inst * 2048 + w * 512], 16, 0, 0);
        }
        #pragma unroll
        for (int inst = 0; inst < NJ; ++inst) {
            int row = inst * 32 + w * 8 + (l >> 3);
            const u16* sb = B + (size_t)(n0 + row) * K + k0 + (lbyte >> 1);
            __builtin_amdgcn_global_load_lds(
                (const AS1 void*)sb,
                (AS3 void*)&ldsB[buf][inst * 2048 + w * 512], 16, 0, 0);
        }
    };

    auto compute = [&](int buf) {
        const char* Ab = (const char*)&ldsA[buf][0];
        const char* Bb = (const char*)&ldsB[buf][0];
        #pragma unroll
        for (int kk = 0; kk < 2; ++kk) {
            int ac2 = kk * 64 + (l >> 4) * 16;
            bf16x8 af[4], bfr[NJ];
            #pragma unroll
            for (int i = 0; i < 4; ++i) {
                int ar = wm + i * 16 + (l & 15);
                af[i] = *(const bf16x8*)(Ab + ar * 128 + (ac2 ^ ((ar & 7) << 4)));
            }
            #pragma unroll
            for (int j = 0; j < NJ; ++j) {
                int br = wn + j * 16 + (l & 15);
                bfr[j] = *(const bf16x8*)(Bb + br * 128 + (ac2 ^ ((br & 7) << 4)));
            }
            #pragma unroll
            for (int i = 0; i < 4; ++i)
                #pragma unroll
                for (int j = 0; j < NJ; ++j)
                    acc[i][j] = __builtin_amdgcn_mfma_f32_16x16x32_bf16(af[i], bfr[j], acc[i][j], 0, 0, 0);
        }
    };

    stage(0, 0);
    const int NT = K >> 6;
    for (int kt = 0; kt < NT; ++kt) {
        __syncthreads();
        if (kt + 1 < NT) stage((kt + 1) & 1, (kt + 1) << 6);
        compute(kt & 1);
    }

    #pragma unroll
    for (int j = 0; j < NJ; ++j) {
        int col = n0 + wn + j * 16 + (l & 15);
        float bv = BIAS ? bias[col] : 0.0f;
        #pragma unroll
        for (int i = 0; i < 4; ++i) {
            int row = m0 + wm + i * 16 + (l >> 4) * 4;
            #pragma unroll
            for (int r = 0; r < 4; ++r) {
                float v = acc[i][j][r] + bv;
                if (OUTBF16)
                    ((u16*)Cout)[(size_t)(row + r) * N + col] = f2bf(v);
                else
                    ((float*)Cout)[(size_t)(row + r) * N + col] = v;
            }
        }
    }
}

// ---------------- RoPE + scatter, cos/sin-deduplicated ----------------
__global__ __launch_bounds__(256)
void rope_scatter2(const u16* __restrict__ qkv,
                   const float* __restrict__ cosb,
                   const float* __restrict__ sinb,
                   u16* __restrict__ Q, u16* __restrict__ Kb, u16* __restrict__ Vt)
{
    int n = blockIdx.x * 256 + threadIdx.x;       // [0, NB*NS*128)
    const int d = n & 127;
    const int bs = n >> 7;                        // b*NS + s
    const int b = bs >> 11, s = bs & 2047;

    const float cs = cosb[(size_t)bs * NHD + d];
    const float sn = sinb[(size_t)bs * NHD + d];
    const int pd = (d < 64) ? d + 64 : d - 64;
    const float psign = (d < 64) ? -1.0f : 1.0f;

    const u16* row = qkv + (size_t)bs * NQKV;

    #pragma unroll
    for (int h = 0; h < NH; ++h) {
        float x = bf2f(row[h * NHD + d]);
        float p = bf2f(row[h * NHD + pd]);
        float v = (x * cs + psign * p * sn) * QSCALE;
        Q[(((size_t)b * NH + h) * NS + s) * NHD + d] = f2bf(v);
    }
    #pragma unroll
    for (int kh = 0; kh < NKH; ++kh) {
        float x = bf2f(row[NH * NHD + kh * NHD + d]);
        float p = bf2f(row[NH * NHD + kh * NHD + pd]);
        float v = x * cs + psign * p * sn;
        Kb[(((size_t)b * NKH + kh) * NS + s) * NHD + d] = f2bf(v);
    }
    #pragma unroll
    for (int vh = 0; vh < NKH; ++vh) {
        Vt[(((size_t)b * NKH + vh) * NHD + d) * NS + s] = row[(NH + NKH) * NHD + vh * NHD + d];
    }
}

// ---------------- causal GQA flash attention v13: single-buffered V, 48KB LDS ----------------
// Head-parallel waves (4 q-heads share one K/V stream per block), balanced
// g pairs (co-resident blocks sum to 33 tiles), K double-buffered, V single-
// buffered. Converged optimum of this family (82 us across 8 variants).
__global__ __launch_bounds__(256, 2)
void attn_fwd13(const u16* __restrict__ Q, const u16* __restrict__ Kb,
                const u16* __restrict__ Vt, u16* __restrict__ Out)
{
    __shared__ u16 kl[2][8192];   // K tile: [64 rows][128 d] bf16, double-buffered
    __shared__ u16 vl[8192];      // V tile: [128 d][64 kv] bf16, single-buffered

    const int l = threadIdx.x & 63;
    const int w = threadIdx.x >> 6;
    const int bid = blockIdx.x;
    const int gi = bid >> 3;
    const int g = (gi < 32) ? (63 - gi) : (gi - 32);   // sweep1: 63..32, sweep2: 0..31
    const int rem = bid & 7;                  // (b, kh, pair)
    const int b = rem & 1;
    const int kh = (rem >> 1) & 1;
    const int h = kh * 8 + ((rem >> 2) & 1) * 4 + w;   // this wave's q-head
    const int c = l & 31, hi = l >> 5;
    const int q0 = g * 32;                    // all 4 waves: same 32 q-rows
    const int qend = q0 + 31;

    const u16* Qp = Q + (((size_t)b * NH + h) * NS + q0) * NHD;
    const u16* Kp = Kb + ((size_t)b * NKH + kh) * NS * NHD;
    const u16* Vp = Vt + ((size_t)b * NKH + kh) * (size_t)NHD * NS;

    bf16x8 qf[8];
    #pragma unroll
    for (int ds = 0; ds < 8; ++ds)
        qf[ds] = *(const bf16x8*)(Qp + c * NHD + ds * 16 + hi * 8);

    f32x16 o0 = {}, o1 = {}, o2 = {}, o3 = {};
    float m_run = -1e30f, l_run = 0.f;

    auto stageK = [&](int buf, int kt) {
        const int kb = kt << 6;
        #pragma unroll
        for (int ii = 0; ii < 4; ++ii) {           // K: rows r, swizzled col chunks
            int r = w * 16 + ii * 4 + (l >> 4);
            int q = (l & 15) ^ ((ii * 4 + (l >> 4)) & 7);
            const u16* src = Kp + (size_t)(kb + r) * NHD + q * 8;
            __builtin_amdgcn_global_load_lds(
                (const AS1 void*)src,
                (AS3 void*)&kl[buf][(w * 4 + ii) * 512], 16, 0, 0);
        }
    };
    auto stageV = [&](int kt) {
        const int kb = kt << 6;
        #pragma unroll
        for (int ii = 0; ii < 4; ++ii) {           // V: rows d, swizzled kv chunks
            int jj = w * 4 + ii;
            int d = jj * 8 + (l >> 3);
            int q = (l & 7) ^ ((l >> 3) & 7);
            const u16* src = Vp + (size_t)d * NS + kb + q * 8;
            __builtin_amdgcn_global_load_lds(
                (const AS1 void*)src,
                (AS3 void*)&vl[jj * 512], 16, 0, 0);
        }
    };

    const int NT = (g >> 1) + 1;               // exact causal range, 64-kv tiles
    stageK(0, 0);
    stageV(0);
    __syncthreads();                           // K(0), V(0) resident

    for (int kt = 0; kt < NT; ++kt) {
        const int kb = kt << 6;
        const int cur = kt & 1;
        if (kt + 1 < NT) stageK(cur ^ 1, kt + 1);

        const bool do1 = (kb + 32 <= qend);
        const bool diag0 = (kb == q0);
        const bool diag1 = (kb + 32 == q0);
        const char* Klb = (const char*)kl[cur];
        const char* Vlb = (const char*)vl;

        f32x16 s0 = {}, s1 = {};
        __builtin_amdgcn_s_setprio(1);
        #pragma unroll
        for (int ds = 0; ds < 8; ++ds) {
            bf16x8 kf0 = *(const bf16x8*)(Klb + c * 256 + ((ds * 32 + hi * 16) ^ ((c & 7) << 4)));
            s0 = __builtin_amdgcn_mfma_f32_32x32x16_bf16(kf0, qf[ds], s0, 0, 0, 0);
        }
        if (do1) {
            #pragma unroll
            for (int ds = 0; ds < 8; ++ds) {
                bf16x8 kf1 = *(const bf16x8*)(Klb + (32 + c) * 256 + ((ds * 32 + hi * 16) ^ ((c & 7) << 4)));
                s1 = __builtin_amdgcn_mfma_f32_32x32x16_bf16(kf1, qf[ds], s1, 0, 0, 0);
            }
        }
        __builtin_amdgcn_s_setprio(0);

        float sv0[16], sv1[16];
        #pragma unroll
        for (int r = 0; r < 16; ++r) { sv0[r] = s0[r]; sv1[r] = do1 ? s1[r] : -1e30f; }

        if (diag0 || diag1) {
            #pragma unroll
            for (int r = 0; r < 16; ++r) {
                int rr = (r & 3) + 8 * (r >> 2) + 4 * hi;
                if (diag0) { if (rr > c) sv0[r] = -1e30f; }
                else       { if (rr > c) sv1[r] = -1e30f; }
            }
        }

        float mx = -1e30f;
        #pragma unroll
        for (int r = 0; r < 16; ++r) mx = fmaxf(mx, fmaxf(sv0[r], sv1[r]));
        mx = redmax32(mx);

        if (__any(mx > m_run + 8.0f)) {
            float mnew = fmaxf(m_run, mx);
            float alpha = exp2f(m_run - mnew);
            m_run = mnew;
            l_run *= alpha;
            #pragma unroll
            for (int r = 0; r < 16; ++r) {
                int qr = (r & 3) + 8 * (r >> 2) + 4 * hi;
                float aR = __shfl(alpha, qr + (l & 32));
                o0[r] *= aR; o1[r] *= aR; o2[r] *= aR; o3[r] *= aR;
            }
        }

        float e0[16], e1[16];
        float ls = 0.f;
        #pragma unroll
        for (int r = 0; r < 16; ++r) {
            e0[r] = exp2f(sv0[r] - m_run);
            e1[r] = exp2f(sv1[r] - m_run);
            ls += e0[r] + e1[r];
        }
        l_run += redsum32(ls);

        bf16x8 pa[4];
        #pragma unroll
        for (int ks = 0; ks < 4; ++ks) {
            const float* pe = (ks < 2) ? e0 : e1;
            const int b8 = (ks & 1) * 8;
            unsigned A  = pk2(pe[b8 + 0], pe[b8 + 1]);
            unsigned Bq = pk2(pe[b8 + 4], pe[b8 + 5]);
            unsigned C2 = pk2(pe[b8 + 2], pe[b8 + 3]);
            unsigned D2 = pk2(pe[b8 + 6], pe[b8 + 7]);
            pl32swap(A, Bq);
            pl32swap(C2, D2);
            union { uint4 u; bf16x8 v; } cv;
            cv.u.x = A;
            cv.u.y = C2;
            cv.u.z = Bq;
            cv.u.w = D2;
            pa[ks] = cv.v;
        }

        __syncthreads();          // drain vmcnt: V(kt) resident (and K(kt+1));
                                  // all waves past QK reads of kl[cur]

        __builtin_amdgcn_s_setprio(1);
        #pragma unroll
        for (int ks = 0; ks < 4; ++ks) {
            if (ks >= 2 && !do1) continue;
            const int ko = (ks * 32 + hi * 16);
            bf16x8 vf;
            vf = *(const bf16x8*)(Vlb + (0 * 32 + c) * 128 + (ko ^ ((c & 7) << 4)));
            o0 = __builtin_amdgcn_mfma_f32_32x32x16_bf16(pa[ks], vf, o0, 0, 0, 0);
            vf = *(const bf16x8*)(Vlb + (1 * 32 + c) * 128 + (ko ^ ((c & 7) << 4)));
            o1 = __builtin_amdgcn_mfma_f32_32x32x16_bf16(pa[ks], vf, o1, 0, 0, 0);
            vf = *(const bf16x8*)(Vlb + (2 * 32 + c) * 128 + (ko ^ ((c & 7) << 4)));
            o2 = __builtin_amdgcn_mfma_f32_32x32x16_bf16(pa[ks], vf, o2, 0, 0, 0);
            vf = *(const bf16x8*)(Vlb + (3 * 32 + c) * 128 + (ko ^ ((c & 7) << 4)));
            o3 = __builtin_amdgcn_mfma_f32_32x32x16_bf16(pa[ks], vf, o3, 0, 0, 0);
        }
        __builtin_amdgcn_s_setprio(0);

        __syncthreads();          // all waves done reading vl
        if (kt + 1 < NT) stageV(kt + 1);   // overwrite vl; lands during next QK
    }

    const float linv = 1.0f / l_run;
    #pragma unroll
    for (int r = 0; r < 16; ++r) {
        int qr = (r & 3) + 8 * (r >> 2) + 4 * hi;
        float lr = __shfl(linv, qr + (l & 32));
        size_t base = ((size_t)(b * NS + q0 + qr)) * (NH * NHD) + h * NHD;
        Out[base + c]      = f2bf(o0[r] * lr);
        Out[base + 32 + c] = f2bf(o1[r] * lr);
        Out[base + 64 + c] = f2bf(o2[r] * lr);
        Out[base + 96 + c] = f2bf(o3[r] * lr);
    }
}

// ---------------- host launcher ----------------
extern "C" void kernel_launch(void* const* d_in, const int* in_sizes, int n_in,
                              void* d_out, int out_size, void* d_ws, size_t ws_size,
                              hipStream_t stream)
{
    (void)in_sizes; (void)n_in; (void)out_size; (void)ws_size;
    const float* hidden = (const float*)d_in[0];
    const float* cosb   = (const float*)d_in[1];
    const float* sinb   = (const float*)d_in[2];
    const float* qkv_w  = (const float*)d_in[3];
    const float* qkv_b  = (const float*)d_in[4];
    const float* o_w    = (const float*)d_in[5];
    float* out = (float*)d_out;

    char* ws = (char*)d_ws;
    size_t off = 0;
    auto alloc = [&](size_t bytes) {
        void* p = ws + off; off += (bytes + 255) & ~(size_t)255; return p;
    };
    u16* hid_bf  = (u16*)alloc((size_t)NB * NS * ND * 2);
    u16* qkvw_bf = (u16*)alloc((size_t)NQKV * ND * 2);
    u16* ow_bf   = (u16*)alloc((size_t)ND * NH * NHD * 2);
    u16* qkv     = (u16*)alloc((size_t)NB * NS * NQKV * 2);
    u16* Qb      = (u16*)alloc((size_t)NB * NH * NS * NHD * 2);
    u16* Kb      = (u16*)alloc((size_t)NB * NKH * NS * NHD * 2);
    u16* Vt      = (u16*)alloc((size_t)NB * NKH * NS * NHD * 2);
    u16* attn    = hid_bf;   // alias: hidden_bf16 dead after GEMM1

    int n1 = NB * NS * ND / 4;
    int n2 = NQKV * ND / 4;
    int n3 = ND * NH * NHD / 4;
    cvt_all<<<(n1 + n2 + n3 + 255) / 256, 256, 0, stream>>>(
        hidden, hid_bf, n1, qkv_w, qkvw_bf, n2, o_w, ow_bf, n3);

    // GEMM1: 128x160 tiles -> 32 x 16 = 512 blocks, exactly 2/CU (no tail)
    int nwg1 = (NB * NS / 128) * (NQKV / 160);     // 512
    gemm_bt<1, 1, 5><<<nwg1, 256, 0, stream>>>(hid_bf, qkvw_bf, qkv_b, qkv,
                                               NB * NS, NQKV, ND, NB * NS / 128, nwg1);

    int nr = NB * NS * NHD;                        // one thread per (bs, d)
    rope_scatter2<<<nr / 256, 256, 0, stream>>>(qkv, cosb, sinb, Qb, Kb, Vt);

    attn_fwd13<<<512, 256, 0, stream>>>(Qb, Kb, Vt, attn);

    int nwg2 = (NB * NS / 128) * (ND / 128);       // 512
    gemm_bt<0, 0, 4><<<nwg2, 256, 0, stream>>>(attn, ow_bf, nullptr, out,
                                               NB * NS, ND, NH * NHD, NB * NS / 128, nwg2);
}